// Round 1
// baseline (814.012 us; speedup 1.0000x reference)
//
#include <hip/hip_runtime.h>

#define N_NODES 100000
#define N_EDGES 1600000
#define FEAT 128
#define N_GRAPHS 1024
#define NB 98  // ceil(N_NODES/1024)

// ---------------- degree / dinv ----------------
__global__ void k_deg(const int* __restrict__ dst, int* __restrict__ deg) {
    int e = blockIdx.x * 256 + threadIdx.x;
    if (e < N_EDGES) atomicAdd(&deg[dst[e]], 1);
}

__global__ void k_dinv(const int* __restrict__ deg, float* __restrict__ dinv) {
    int i = blockIdx.x * 256 + threadIdx.x;
    if (i < N_NODES) dinv[i] = rsqrtf((float)(deg[i] + 1));  // +1 self-loop
}

// ---------------- exclusive scan of deg -> offs (3-phase) ----------------
__global__ __launch_bounds__(1024) void k_blocksum(const int* __restrict__ deg,
                                                   int* __restrict__ bsums) {
    int i = blockIdx.x * 1024 + threadIdx.x;
    int v = (i < N_NODES) ? deg[i] : 0;
#pragma unroll
    for (int d = 32; d > 0; d >>= 1) v += __shfl_down(v, d);
    __shared__ int wsum[16];
    int lane = threadIdx.x & 63, wid = threadIdx.x >> 6;
    if (lane == 0) wsum[wid] = v;
    __syncthreads();
    if (threadIdx.x < 16) {
        int s = wsum[threadIdx.x];
#pragma unroll
        for (int d = 8; d > 0; d >>= 1) s += __shfl_down(s, d);
        if (threadIdx.x == 0) bsums[blockIdx.x] = s;
    }
}

__global__ void k_scan2(int* __restrict__ bsums) {
    if (threadIdx.x == 0) {
        int a = 0;
        for (int i = 0; i < NB; ++i) { int t = bsums[i]; bsums[i] = a; a += t; }
    }
}

__global__ __launch_bounds__(1024) void k_scanwrite(const int* __restrict__ deg,
                                                    const int* __restrict__ bsums,
                                                    int* __restrict__ offs,
                                                    int* __restrict__ cur) {
    int i = blockIdx.x * 1024 + threadIdx.x;
    int orig = (i < N_NODES) ? deg[i] : 0;
    int v = orig;
    int lane = threadIdx.x & 63, wid = threadIdx.x >> 6;
#pragma unroll
    for (int d = 1; d < 64; d <<= 1) {
        int n = __shfl_up(v, d);
        if (lane >= d) v += n;
    }
    __shared__ int ws[16];
    if (lane == 63) ws[wid] = v;
    __syncthreads();
    if (threadIdx.x < 16) {
        int s = ws[threadIdx.x];
#pragma unroll
        for (int d = 1; d < 16; d <<= 1) {
            int n = __shfl_up(s, d);
            if ((int)threadIdx.x >= d) s += n;
        }
        ws[threadIdx.x] = s;
    }
    __syncthreads();
    int excl = v - orig + (wid ? ws[wid - 1] : 0) + bsums[blockIdx.x];
    if (i < N_NODES) { offs[i] = excl; cur[i] = excl; }
    if (i == N_NODES) offs[N_NODES] = N_EDGES;
}

// ---------------- CSR fill ----------------
__global__ void k_fill(const int* __restrict__ src, const int* __restrict__ dst,
                       int* __restrict__ cur, int* __restrict__ csr) {
    int e = blockIdx.x * 256 + threadIdx.x;
    if (e < N_EDGES) {
        int d = dst[e];
        int p = atomicAdd(&cur[d], 1);
        csr[p] = src[e];
    }
}

// ---------------- GEMM (inp @ W), row-scaled by dinv -> u ----------------
// 64 rows/block, 256 threads. thread (tx,ty): cols tx*4..tx*4+3, rows ty+8j.
__global__ __launch_bounds__(256) void k_gemm_scale(const float* __restrict__ inp,
                                                    const float* __restrict__ W,
                                                    const float* __restrict__ dinv,
                                                    float* __restrict__ u) {
    __shared__ float sW[64 * 128];  // [k][c] chunk
    __shared__ float sIn[64 * 64];  // [row][k] chunk
    int t = threadIdx.x;
    int tx = t & 31, ty = t >> 5;
    int row0 = blockIdx.x * 64;
    float4 acc[8];
#pragma unroll
    for (int j = 0; j < 8; j++) acc[j] = make_float4(0.f, 0.f, 0.f, 0.f);

    for (int k0 = 0; k0 < 128; k0 += 64) {
        __syncthreads();
        {
            float4* d4 = (float4*)sW;
            const float4* s4 = (const float4*)(W + k0 * 128);
#pragma unroll
            for (int q = 0; q < 8; q++) d4[t + 256 * q] = s4[t + 256 * q];
        }
        {
            float4* d4 = (float4*)sIn;
#pragma unroll
            for (int q = 0; q < 4; q++) {
                int idx = t + 256 * q;
                int r = idx >> 4, c4 = idx & 15;
                int row = row0 + r;
                float4 v = make_float4(0.f, 0.f, 0.f, 0.f);
                if (row < N_NODES)
                    v = *(const float4*)(inp + (size_t)row * 128 + k0 + c4 * 4);
                d4[idx] = v;
            }
        }
        __syncthreads();
        const float4* sW4 = (const float4*)sW;    // [64][32]
        const float4* sIn4 = (const float4*)sIn;  // [64][16]
#pragma unroll
        for (int kk = 0; kk < 64; kk += 4) {
            float4 w0 = sW4[(kk + 0) * 32 + tx];
            float4 w1 = sW4[(kk + 1) * 32 + tx];
            float4 w2 = sW4[(kk + 2) * 32 + tx];
            float4 w3 = sW4[(kk + 3) * 32 + tx];
#pragma unroll
            for (int j = 0; j < 8; j++) {
                float4 a = sIn4[(ty + 8 * j) * 16 + (kk >> 2)];
                acc[j].x += a.x * w0.x + a.y * w1.x + a.z * w2.x + a.w * w3.x;
                acc[j].y += a.x * w0.y + a.y * w1.y + a.z * w2.y + a.w * w3.y;
                acc[j].z += a.x * w0.z + a.y * w1.z + a.z * w2.z + a.w * w3.z;
                acc[j].w += a.x * w0.w + a.y * w1.w + a.z * w2.w + a.w * w3.w;
            }
        }
    }
#pragma unroll
    for (int j = 0; j < 8; j++) {
        int row = row0 + ty + 8 * j;
        if (row < N_NODES) {
            float d = dinv[row];
            float4 o = make_float4(d * acc[j].x, d * acc[j].y, d * acc[j].z, d * acc[j].w);
            *(float4*)(u + (size_t)row * 128 + tx * 4) = o;
        }
    }
}

// ---------------- aggregate: h[i] = relu(dinv[i]*(sum_in u[src] + u[i]) + b) ----------------
// one wave per node; lane handles 2 cols (float2).
__global__ __launch_bounds__(256) void k_agg(const float* __restrict__ u,
                                             const int* __restrict__ offs,
                                             const int* __restrict__ csr,
                                             const float* __restrict__ dinv,
                                             const float* __restrict__ bias,
                                             float* __restrict__ hout) {
    int wid = threadIdx.x >> 6;
    int lane = threadIdx.x & 63;
    int node = blockIdx.x * 4 + wid;
    if (node >= N_NODES) return;
    const float2* u2 = (const float2*)u;
    float2 a0 = u2[(size_t)node * 64 + lane];  // self-loop term
    float2 a1 = make_float2(0.f, 0.f);
    float2 a2 = make_float2(0.f, 0.f);
    float2 a3 = make_float2(0.f, 0.f);
    int p = offs[node], e = offs[node + 1];
    for (; p + 3 < e; p += 4) {
        int s0 = csr[p], s1 = csr[p + 1], s2 = csr[p + 2], s3 = csr[p + 3];
        float2 v0 = u2[(size_t)s0 * 64 + lane];
        float2 v1 = u2[(size_t)s1 * 64 + lane];
        float2 v2 = u2[(size_t)s2 * 64 + lane];
        float2 v3 = u2[(size_t)s3 * 64 + lane];
        a0.x += v0.x; a0.y += v0.y;
        a1.x += v1.x; a1.y += v1.y;
        a2.x += v2.x; a2.y += v2.y;
        a3.x += v3.x; a3.y += v3.y;
    }
    for (; p < e; ++p) {
        int s0 = csr[p];
        float2 v0 = u2[(size_t)s0 * 64 + lane];
        a0.x += v0.x; a0.y += v0.y;
    }
    float d = dinv[node];
    float2 b = ((const float2*)bias)[lane];
    float sx = a0.x + a1.x + a2.x + a3.x;
    float sy = a0.y + a1.y + a2.y + a3.y;
    float r0 = fmaxf(d * sx + b.x, 0.f);
    float r1 = fmaxf(d * sy + b.y, 0.f);
    ((float2*)hout)[(size_t)node * 64 + lane] = make_float2(r0, r1);
}

// ---------------- pool (batch sorted) + linear head ----------------
__global__ __launch_bounds__(128) void k_pool(const float* __restrict__ h,
                                              const int* __restrict__ batch,
                                              const float* __restrict__ Wl,
                                              const float* __restrict__ bl,
                                              float* __restrict__ out) {
    int g = blockIdx.x;
    int c = threadIdx.x;  // 0..127
    __shared__ int sb[2];
    if (c < 2) {
        int tgt = g + c;
        int lo = 0, hi = N_NODES;
        while (lo < hi) { int m = (lo + hi) >> 1; if (batch[m] < tgt) lo = m + 1; else hi = m; }
        sb[c] = lo;
    }
    __syncthreads();
    int s0 = sb[0], s1 = sb[1];
    float sum = 0.f;
    for (int i = s0; i < s1; ++i) sum += h[(size_t)i * 128 + c];
    float cnt = (float)(s1 - s0);
    float pooled = sum / fmaxf(cnt, 1.0f);
    __shared__ float red[128];
    float w0 = Wl[c * 2 + 0], w1 = Wl[c * 2 + 1];
    red[c] = pooled * w0;
    __syncthreads();
    for (int st = 64; st > 0; st >>= 1) { if (c < st) red[c] += red[c + st]; __syncthreads(); }
    if (c == 0) out[g * 2 + 0] = red[0] + bl[0];
    __syncthreads();
    red[c] = pooled * w1;
    __syncthreads();
    for (int st = 64; st > 0; st >>= 1) { if (c < st) red[c] += red[c + st]; __syncthreads(); }
    if (c == 0) out[g * 2 + 1] = red[0] + bl[1];
}

extern "C" void kernel_launch(void* const* d_in, const int* in_sizes, int n_in,
                              void* d_out, int out_size, void* d_ws, size_t ws_size,
                              hipStream_t stream) {
    const float* x  = (const float*)d_in[0];
    const int* ei   = (const int*)d_in[1];
    const int* batch = (const int*)d_in[2];
    const float* W1 = (const float*)d_in[3];
    const float* b1 = (const float*)d_in[4];
    const float* W2 = (const float*)d_in[5];
    const float* b2 = (const float*)d_in[6];
    const float* Wl = (const float*)d_in[7];
    const float* bl = (const float*)d_in[8];
    float* out = (float*)d_out;
    const int* src = ei;
    const int* dst = ei + N_EDGES;

    char* ws = (char*)d_ws;
    size_t o = 0;
    auto alloc = [&](size_t bytes) -> void* {
        o = (o + 255) & ~(size_t)255;
        void* p = ws + o;
        o += bytes;
        return p;
    };
    int* deg    = (int*)alloc((size_t)N_NODES * 4);
    float* dinv = (float*)alloc((size_t)N_NODES * 4);
    int* offs   = (int*)alloc((size_t)(N_NODES + 1) * 4);
    int* cur    = (int*)alloc((size_t)N_NODES * 4);
    int* bsums  = (int*)alloc((size_t)NB * 4);
    int* csr    = (int*)alloc((size_t)N_EDGES * 4);
    float* u    = (float*)alloc((size_t)N_NODES * 128 * 4);
    float* h    = (float*)alloc((size_t)N_NODES * 128 * 4);

    hipMemsetAsync(deg, 0, (size_t)N_NODES * 4, stream);
    k_deg<<<(N_EDGES + 255) / 256, 256, 0, stream>>>(dst, deg);
    k_dinv<<<(N_NODES + 255) / 256, 256, 0, stream>>>(deg, dinv);
    k_blocksum<<<NB, 1024, 0, stream>>>(deg, bsums);
    k_scan2<<<1, 64, 0, stream>>>(bsums);
    k_scanwrite<<<NB, 1024, 0, stream>>>(deg, bsums, offs, cur);
    k_fill<<<(N_EDGES + 255) / 256, 256, 0, stream>>>(src, dst, cur, csr);

    k_gemm_scale<<<(N_NODES + 63) / 64, 256, 0, stream>>>(x, W1, dinv, u);
    k_agg<<<(N_NODES + 3) / 4, 256, 0, stream>>>(u, offs, csr, dinv, b1, h);
    k_gemm_scale<<<(N_NODES + 63) / 64, 256, 0, stream>>>(h, W2, dinv, u);
    k_agg<<<(N_NODES + 3) / 4, 256, 0, stream>>>(u, offs, csr, dinv, b2, h);

    k_pool<<<N_GRAPHS, 128, 0, stream>>>(h, batch, Wl, bl, out);
}

// Round 2
// 599.870 us; speedup vs baseline: 1.3570x; 1.3570x over previous
//
#include <hip/hip_runtime.h>
#include <hip/hip_bf16.h>

#define N_NODES 100000
#define N_EDGES 1600000
#define FEAT 128
#define N_GRAPHS 1024
#define NB 98  // ceil(N_NODES/1024)

static __device__ inline unsigned short f2bf(float f) {
    __hip_bfloat16 b = __float2bfloat16(f);
    unsigned short r;
    __builtin_memcpy(&r, &b, 2);
    return r;
}
static __device__ inline float bf_lo(unsigned int v) { return __uint_as_float(v << 16); }
static __device__ inline float bf_hi(unsigned int v) { return __uint_as_float(v & 0xFFFF0000u); }

// ---------------- degree / dinv ----------------
__global__ void k_deg(const int* __restrict__ dst, int* __restrict__ deg) {
    int e = blockIdx.x * 256 + threadIdx.x;
    if (e < N_EDGES) atomicAdd(&deg[dst[e]], 1);
}

__global__ void k_dinv(const int* __restrict__ deg, float* __restrict__ dinv) {
    int i = blockIdx.x * 256 + threadIdx.x;
    if (i < N_NODES) dinv[i] = rsqrtf((float)(deg[i] + 1));  // +1 self-loop
}

// ---------------- exclusive scan of deg -> offs (3-phase) ----------------
__global__ __launch_bounds__(1024) void k_blocksum(const int* __restrict__ deg,
                                                   int* __restrict__ bsums) {
    int i = blockIdx.x * 1024 + threadIdx.x;
    int v = (i < N_NODES) ? deg[i] : 0;
#pragma unroll
    for (int d = 32; d > 0; d >>= 1) v += __shfl_down(v, d);
    __shared__ int wsum[16];
    int lane = threadIdx.x & 63, wid = threadIdx.x >> 6;
    if (lane == 0) wsum[wid] = v;
    __syncthreads();
    if (threadIdx.x < 16) {
        int s = wsum[threadIdx.x];
#pragma unroll
        for (int d = 8; d > 0; d >>= 1) s += __shfl_down(s, d);
        if (threadIdx.x == 0) bsums[blockIdx.x] = s;
    }
}

__global__ void k_scan2(int* __restrict__ bsums) {
    if (threadIdx.x == 0) {
        int a = 0;
        for (int i = 0; i < NB; ++i) { int t = bsums[i]; bsums[i] = a; a += t; }
    }
}

__global__ __launch_bounds__(1024) void k_scanwrite(const int* __restrict__ deg,
                                                    const int* __restrict__ bsums,
                                                    int* __restrict__ offs,
                                                    int* __restrict__ cur) {
    int i = blockIdx.x * 1024 + threadIdx.x;
    int orig = (i < N_NODES) ? deg[i] : 0;
    int v = orig;
    int lane = threadIdx.x & 63, wid = threadIdx.x >> 6;
#pragma unroll
    for (int d = 1; d < 64; d <<= 1) {
        int n = __shfl_up(v, d);
        if (lane >= d) v += n;
    }
    __shared__ int ws[16];
    if (lane == 63) ws[wid] = v;
    __syncthreads();
    if (threadIdx.x < 16) {
        int s = ws[threadIdx.x];
#pragma unroll
        for (int d = 1; d < 16; d <<= 1) {
            int n = __shfl_up(s, d);
            if ((int)threadIdx.x >= d) s += n;
        }
        ws[threadIdx.x] = s;
    }
    __syncthreads();
    int excl = v - orig + (wid ? ws[wid - 1] : 0) + bsums[blockIdx.x];
    if (i < N_NODES) { offs[i] = excl; cur[i] = excl; }
    if (i == N_NODES) offs[N_NODES] = N_EDGES;
}

// ---------------- CSR fill ----------------
__global__ void k_fill(const int* __restrict__ src, const int* __restrict__ dst,
                       int* __restrict__ cur, int* __restrict__ csr) {
    int e = blockIdx.x * 256 + threadIdx.x;
    if (e < N_EDGES) {
        int d = dst[e];
        int p = atomicAdd(&cur[d], 1);
        csr[p] = src[e];
    }
}

// ---------------- GEMM: u = bf16( dinv .* (inp @ W) ), persistent blocks ----------------
// Block: 256 threads. blockIdx&1 selects col-half (64 cols, W-half in 32KB LDS, loaded once).
// Grid-stride over 64-row tiles. Thread (tx=t&15, ty=t>>4): cols c0+tx*4..+3, rows ty+16j.
__device__ inline void fma4(float4& a, float s, const float4& w) {
    a.x = fmaf(s, w.x, a.x); a.y = fmaf(s, w.y, a.y);
    a.z = fmaf(s, w.z, a.z); a.w = fmaf(s, w.w, a.w);
}

__global__ __launch_bounds__(256) void k_gemm_scale(const float* __restrict__ inp,
                                                    const float* __restrict__ W,
                                                    const float* __restrict__ dinv,
                                                    unsigned short* __restrict__ u) {
    __shared__ float sW[128 * 64];
    const int t = threadIdx.x;
    const int ch = blockIdx.x & 1;
    const int c0 = ch * 64;
    {
        float4* d4 = (float4*)sW;
        const float4* s4 = (const float4*)W;
#pragma unroll
        for (int q = 0; q < 8; ++q) {
            int idx = t + 256 * q;           // 2048 float4 total
            int k = idx >> 4, cc = idx & 15; // sW[k][cc*4..]
            d4[idx] = s4[k * 32 + ch * 16 + cc];
        }
    }
    __syncthreads();
    const int tx = t & 15, ty = t >> 4;
    const float4* sW4 = (const float4*)sW;
    const int nTiles = (N_NODES + 63) >> 6;
    for (int tile = blockIdx.x >> 1; tile < nTiles; tile += gridDim.x >> 1) {
        int row0 = tile << 6;
        int r[4]; bool vld[4];
#pragma unroll
        for (int j = 0; j < 4; ++j) {
            int rr = row0 + ty + 16 * j;
            vld[j] = rr < N_NODES;
            r[j] = vld[j] ? rr : (N_NODES - 1);
        }
        const float4* p0 = (const float4*)(inp + (size_t)r[0] * 128);
        const float4* p1 = (const float4*)(inp + (size_t)r[1] * 128);
        const float4* p2 = (const float4*)(inp + (size_t)r[2] * 128);
        const float4* p3 = (const float4*)(inp + (size_t)r[3] * 128);
        float4 acc0 = {0, 0, 0, 0}, acc1 = {0, 0, 0, 0};
        float4 acc2 = {0, 0, 0, 0}, acc3 = {0, 0, 0, 0};
#pragma unroll 4
        for (int k4 = 0; k4 < 32; ++k4) {
            float4 a0 = p0[k4], a1 = p1[k4], a2 = p2[k4], a3 = p3[k4];
            float4 w0 = sW4[(k4 * 4 + 0) * 16 + tx];
            float4 w1 = sW4[(k4 * 4 + 1) * 16 + tx];
            float4 w2 = sW4[(k4 * 4 + 2) * 16 + tx];
            float4 w3 = sW4[(k4 * 4 + 3) * 16 + tx];
            fma4(acc0, a0.x, w0); fma4(acc0, a0.y, w1); fma4(acc0, a0.z, w2); fma4(acc0, a0.w, w3);
            fma4(acc1, a1.x, w0); fma4(acc1, a1.y, w1); fma4(acc1, a1.z, w2); fma4(acc1, a1.w, w3);
            fma4(acc2, a2.x, w0); fma4(acc2, a2.y, w1); fma4(acc2, a2.z, w2); fma4(acc2, a2.w, w3);
            fma4(acc3, a3.x, w0); fma4(acc3, a3.y, w1); fma4(acc3, a3.z, w2); fma4(acc3, a3.w, w3);
        }
        float4 accs[4] = {acc0, acc1, acc2, acc3};
#pragma unroll
        for (int j = 0; j < 4; ++j) {
            if (vld[j]) {
                float d = dinv[r[j]];
                ushort4 o;
                o.x = f2bf(d * accs[j].x);
                o.y = f2bf(d * accs[j].y);
                o.z = f2bf(d * accs[j].z);
                o.w = f2bf(d * accs[j].w);
                *(ushort4*)(u + (size_t)r[j] * 128 + c0 + tx * 4) = o;
            }
        }
    }
}

// ---------------- aggregate: h[i] = relu(dinv[i]*(sum_in u[src] + u[i]) + b) ----------------
// u is bf16[N][128]; one wave per node; lane handles cols 2*lane, 2*lane+1 (one uint load).
__global__ __launch_bounds__(256) void k_agg(const unsigned int* __restrict__ u,
                                             const int* __restrict__ offs,
                                             const int* __restrict__ csr,
                                             const float* __restrict__ dinv,
                                             const float* __restrict__ bias,
                                             float* __restrict__ hout) {
    int wid = threadIdx.x >> 6;
    int lane = threadIdx.x & 63;
    int node = blockIdx.x * 4 + wid;
    if (node >= N_NODES) return;
    unsigned int self = u[(size_t)node * 64 + lane];
    float a0x = bf_lo(self), a0y = bf_hi(self);
    float a1x = 0.f, a1y = 0.f, a2x = 0.f, a2y = 0.f, a3x = 0.f, a3y = 0.f;
    int p = offs[node], e = offs[node + 1];
    for (; p + 3 < e; p += 4) {
        int s0 = csr[p], s1 = csr[p + 1], s2 = csr[p + 2], s3 = csr[p + 3];
        unsigned int v0 = u[(size_t)s0 * 64 + lane];
        unsigned int v1 = u[(size_t)s1 * 64 + lane];
        unsigned int v2 = u[(size_t)s2 * 64 + lane];
        unsigned int v3 = u[(size_t)s3 * 64 + lane];
        a0x += bf_lo(v0); a0y += bf_hi(v0);
        a1x += bf_lo(v1); a1y += bf_hi(v1);
        a2x += bf_lo(v2); a2y += bf_hi(v2);
        a3x += bf_lo(v3); a3y += bf_hi(v3);
    }
    for (; p < e; ++p) {
        unsigned int v0 = u[(size_t)csr[p] * 64 + lane];
        a0x += bf_lo(v0); a0y += bf_hi(v0);
    }
    float d = dinv[node];
    float2 b = ((const float2*)bias)[lane];
    float sx = a0x + a1x + a2x + a3x;
    float sy = a0y + a1y + a2y + a3y;
    float r0 = fmaxf(d * sx + b.x, 0.f);
    float r1 = fmaxf(d * sy + b.y, 0.f);
    ((float2*)hout)[(size_t)node * 64 + lane] = make_float2(r0, r1);
}

// ---------------- pool (batch sorted) + linear head ----------------
__global__ __launch_bounds__(128) void k_pool(const float* __restrict__ h,
                                              const int* __restrict__ batch,
                                              const float* __restrict__ Wl,
                                              const float* __restrict__ bl,
                                              float* __restrict__ out) {
    int g = blockIdx.x;
    int c = threadIdx.x;  // 0..127
    __shared__ int sb[2];
    if (c < 2) {
        int tgt = g + c;
        int lo = 0, hi = N_NODES;
        while (lo < hi) { int m = (lo + hi) >> 1; if (batch[m] < tgt) lo = m + 1; else hi = m; }
        sb[c] = lo;
    }
    __syncthreads();
    int s0 = sb[0], s1 = sb[1];
    float sum = 0.f;
    for (int i = s0; i < s1; ++i) sum += h[(size_t)i * 128 + c];
    float cnt = (float)(s1 - s0);
    float pooled = sum / fmaxf(cnt, 1.0f);
    __shared__ float red[128];
    float w0 = Wl[c * 2 + 0], w1 = Wl[c * 2 + 1];
    red[c] = pooled * w0;
    __syncthreads();
    for (int st = 64; st > 0; st >>= 1) { if (c < st) red[c] += red[c + st]; __syncthreads(); }
    if (c == 0) out[g * 2 + 0] = red[0] + bl[0];
    __syncthreads();
    red[c] = pooled * w1;
    __syncthreads();
    for (int st = 64; st > 0; st >>= 1) { if (c < st) red[c] += red[c + st]; __syncthreads(); }
    if (c == 0) out[g * 2 + 1] = red[0] + bl[1];
}

extern "C" void kernel_launch(void* const* d_in, const int* in_sizes, int n_in,
                              void* d_out, int out_size, void* d_ws, size_t ws_size,
                              hipStream_t stream) {
    const float* x  = (const float*)d_in[0];
    const int* ei   = (const int*)d_in[1];
    const int* batch = (const int*)d_in[2];
    const float* W1 = (const float*)d_in[3];
    const float* b1 = (const float*)d_in[4];
    const float* W2 = (const float*)d_in[5];
    const float* b2 = (const float*)d_in[6];
    const float* Wl = (const float*)d_in[7];
    const float* bl = (const float*)d_in[8];
    float* out = (float*)d_out;
    const int* src = ei;
    const int* dst = ei + N_EDGES;

    char* ws = (char*)d_ws;
    size_t o = 0;
    auto alloc = [&](size_t bytes) -> void* {
        o = (o + 255) & ~(size_t)255;
        void* p = ws + o;
        o += bytes;
        return p;
    };
    int* deg    = (int*)alloc((size_t)N_NODES * 4);
    float* dinv = (float*)alloc((size_t)N_NODES * 4);
    int* offs   = (int*)alloc((size_t)(N_NODES + 1) * 4);
    int* cur    = (int*)alloc((size_t)N_NODES * 4);
    int* bsums  = (int*)alloc((size_t)NB * 4);
    int* csr    = (int*)alloc((size_t)N_EDGES * 4);
    unsigned short* u = (unsigned short*)alloc((size_t)N_NODES * 128 * 2);  // bf16
    float* h    = (float*)alloc((size_t)N_NODES * 128 * 4);

    hipMemsetAsync(deg, 0, (size_t)N_NODES * 4, stream);
    k_deg<<<(N_EDGES + 255) / 256, 256, 0, stream>>>(dst, deg);
    k_dinv<<<(N_NODES + 255) / 256, 256, 0, stream>>>(deg, dinv);
    k_blocksum<<<NB, 1024, 0, stream>>>(deg, bsums);
    k_scan2<<<1, 64, 0, stream>>>(bsums);
    k_scanwrite<<<NB, 1024, 0, stream>>>(deg, bsums, offs, cur);
    k_fill<<<(N_EDGES + 255) / 256, 256, 0, stream>>>(src, dst, cur, csr);

    k_gemm_scale<<<1024, 256, 0, stream>>>(x, W1, dinv, u);
    k_agg<<<(N_NODES + 3) / 4, 256, 0, stream>>>((const unsigned int*)u, offs, csr, dinv, b1, h);
    k_gemm_scale<<<1024, 256, 0, stream>>>(h, W2, dinv, u);
    k_agg<<<(N_NODES + 3) / 4, 256, 0, stream>>>((const unsigned int*)u, offs, csr, dinv, b2, h);

    k_pool<<<N_GRAPHS, 128, 0, stream>>>(h, batch, Wl, bl, out);
}

// Round 3
// 466.416 us; speedup vs baseline: 1.7452x; 1.2861x over previous
//
#include <hip/hip_runtime.h>
#include <hip/hip_bf16.h>

#define N_NODES 100000
#define N_EDGES 1600000
#define FEAT 128
#define N_GRAPHS 1024
#define NBUCK 391   // ceil(N_NODES/256) windows of 256 nodes (bucket = dst >> 8)
#define CHUNK 4096  // edges per k_bucket block

static __device__ inline unsigned short f2bf(float f) {
    __hip_bfloat16 b = __float2bfloat16(f);
    unsigned short r;
    __builtin_memcpy(&r, &b, 2);
    return r;
}
static __device__ inline float bf_lo(unsigned int v) { return __uint_as_float(v << 16); }
static __device__ inline float bf_hi(unsigned int v) { return __uint_as_float(v & 0xFFFF0000u); }

// ---------------- bucket histogram (LDS-staged) ----------------
__global__ __launch_bounds__(256) void k_hist(const int* __restrict__ dst,
                                              int* __restrict__ bcount) {
    __shared__ int h[NBUCK];
    for (int i = threadIdx.x; i < NBUCK; i += 256) h[i] = 0;
    __syncthreads();
    for (int e = blockIdx.x * 256 + threadIdx.x; e < N_EDGES; e += gridDim.x * 256)
        atomicAdd(&h[dst[e] >> 8], 1);
    __syncthreads();
    for (int i = threadIdx.x; i < NBUCK; i += 256) {
        int c = h[i];
        if (c) atomicAdd(&bcount[i], c);
    }
}

// ---------------- exclusive scan of 391 values (single block) ----------------
__global__ __launch_bounds__(512) void k_scan391(const int* __restrict__ in,
                                                 int* __restrict__ base,
                                                 int* __restrict__ cur,
                                                 int* __restrict__ tail) {
    int t = threadIdx.x;
    int v = (t < NBUCK) ? in[t] : 0;
    int lane = t & 63, wid = t >> 6;
    int s = v;
#pragma unroll
    for (int d = 1; d < 64; d <<= 1) { int n = __shfl_up(s, d); if (lane >= d) s += n; }
    __shared__ int ws[8];
    if (lane == 63) ws[wid] = s;
    __syncthreads();
    if (t < 8) {
        int x = ws[t];
#pragma unroll
        for (int d = 1; d < 8; d <<= 1) { int n = __shfl_up(x, d); if ((int)t >= d) x += n; }
        ws[t] = x;
    }
    __syncthreads();
    int excl = s - v + (wid ? ws[wid - 1] : 0);
    if (t < NBUCK) {
        base[t] = excl;
        if (cur) cur[t] = excl;
    }
    if (t == 0 && tail) tail[0] = N_EDGES;
}

// ---------------- bin edges into bucket runs (block counting-sort) ----------------
__global__ __launch_bounds__(256) void k_bucket(const int* __restrict__ src,
                                                const int* __restrict__ dst,
                                                int* __restrict__ bcur,
                                                uint2* __restrict__ pairs) {
    __shared__ int cnt[NBUCK];
    __shared__ int basebuf[NBUCK];
    int t = threadIdx.x;
    int e0 = blockIdx.x * CHUNK;
    for (int i = t; i < NBUCK; i += 256) cnt[i] = 0;
    __syncthreads();
    int es[16], ed[16];
#pragma unroll
    for (int j = 0; j < 16; ++j) {
        int e = e0 + j * 256 + t;
        if (e < N_EDGES) {
            es[j] = src[e];
            ed[j] = dst[e];
            atomicAdd(&cnt[ed[j] >> 8], 1);
        } else ed[j] = -1;
    }
    __syncthreads();
    for (int i = t; i < NBUCK; i += 256) {
        int c = cnt[i];
        basebuf[i] = c ? atomicAdd(&bcur[i], c) : 0;
        cnt[i] = 0;
    }
    __syncthreads();
#pragma unroll
    for (int j = 0; j < 16; ++j) {
        if (ed[j] >= 0) {
            int b = ed[j] >> 8;
            int p = basebuf[b] + atomicAdd(&cnt[b], 1);
            pairs[p] = make_uint2((unsigned)es[j], (unsigned)ed[j]);
        }
    }
}

// ---------------- per-bucket degree via LDS atomics ----------------
__global__ __launch_bounds__(256) void k_bdeg(const uint2* __restrict__ pairs,
                                              const int* __restrict__ bbase,
                                              const int* __restrict__ bcount,
                                              int* __restrict__ deg,
                                              int* __restrict__ wsum) {
    __shared__ int d[256];
    __shared__ int wr[4];
    int b = blockIdx.x, t = threadIdx.x;
    d[t] = 0;
    __syncthreads();
    int s0 = bbase[b], n = bcount[b];
    for (int i = t; i < n; i += 256) atomicAdd(&d[pairs[s0 + i].y & 255], 1);
    __syncthreads();
    int node = b * 256 + t;
    int v = d[t];
    if (node < N_NODES) deg[node] = v;
#pragma unroll
    for (int dd = 32; dd > 0; dd >>= 1) v += __shfl_down(v, dd);
    if ((t & 63) == 0) wr[t >> 6] = v;
    __syncthreads();
    if (t == 0) wsum[b] = wr[0] + wr[1] + wr[2] + wr[3];
}

__global__ void k_dinv(const int* __restrict__ deg, float* __restrict__ dinv) {
    int i = blockIdx.x * 256 + threadIdx.x;
    if (i < N_NODES) dinv[i] = rsqrtf((float)(deg[i] + 1));  // +1 self-loop
}

// ---------------- per-bucket CSR fill (L2-local scatter) ----------------
__global__ __launch_bounds__(256) void k_bfill(const uint2* __restrict__ pairs,
                                               const int* __restrict__ bbase,
                                               const int* __restrict__ bcount,
                                               const int* __restrict__ deg,
                                               const int* __restrict__ wbase,
                                               int* __restrict__ offs,
                                               int* __restrict__ csr) {
    __shared__ int lcur[256];
    __shared__ int ws[4];
    int b = blockIdx.x, t = threadIdx.x;
    int node = b * 256 + t;
    int dv = (node < N_NODES) ? deg[node] : 0;
    int lane = t & 63, wid = t >> 6;
    int s = dv;
#pragma unroll
    for (int d = 1; d < 64; d <<= 1) { int n = __shfl_up(s, d); if (lane >= d) s += n; }
    if (lane == 63) ws[wid] = s;
    __syncthreads();
    if (t < 4) {
        int x = ws[t];
#pragma unroll
        for (int d = 1; d < 4; d <<= 1) { int n = __shfl_up(x, d); if ((int)t >= d) x += n; }
        ws[t] = x;
    }
    __syncthreads();
    int excl = s - dv + (wid ? ws[wid - 1] : 0) + wbase[b];
    if (node < N_NODES) offs[node] = excl;
    lcur[t] = excl;
    __syncthreads();
    int s0 = bbase[b], n = bcount[b];
    for (int i = t; i < n; i += 256) {
        uint2 pr = pairs[s0 + i];
        int p = atomicAdd(&lcur[pr.y & 255], 1);
        csr[p] = (int)pr.x;
    }
}

// ---------------- GEMM: u = bf16( dinv .* (inp @ W) ), persistent blocks ----------------
__device__ inline void fma4(float4& a, float s, const float4& w) {
    a.x = fmaf(s, w.x, a.x); a.y = fmaf(s, w.y, a.y);
    a.z = fmaf(s, w.z, a.z); a.w = fmaf(s, w.w, a.w);
}

__global__ __launch_bounds__(256) void k_gemm_scale(const float* __restrict__ inp,
                                                    const float* __restrict__ W,
                                                    const float* __restrict__ dinv,
                                                    unsigned short* __restrict__ u) {
    __shared__ float sW[128 * 64];
    const int t = threadIdx.x;
    const int ch = blockIdx.x & 1;
    const int c0 = ch * 64;
    {
        float4* d4 = (float4*)sW;
        const float4* s4 = (const float4*)W;
#pragma unroll
        for (int q = 0; q < 8; ++q) {
            int idx = t + 256 * q;
            int k = idx >> 4, cc = idx & 15;
            d4[idx] = s4[k * 32 + ch * 16 + cc];
        }
    }
    __syncthreads();
    const int tx = t & 15, ty = t >> 4;
    const float4* sW4 = (const float4*)sW;
    const int nTiles = (N_NODES + 63) >> 6;
    for (int tile = blockIdx.x >> 1; tile < nTiles; tile += gridDim.x >> 1) {
        int row0 = tile << 6;
        int r[4]; bool vld[4];
#pragma unroll
        for (int j = 0; j < 4; ++j) {
            int rr = row0 + ty + 16 * j;
            vld[j] = rr < N_NODES;
            r[j] = vld[j] ? rr : (N_NODES - 1);
        }
        const float4* p0 = (const float4*)(inp + (size_t)r[0] * 128);
        const float4* p1 = (const float4*)(inp + (size_t)r[1] * 128);
        const float4* p2 = (const float4*)(inp + (size_t)r[2] * 128);
        const float4* p3 = (const float4*)(inp + (size_t)r[3] * 128);
        float4 acc0 = {0, 0, 0, 0}, acc1 = {0, 0, 0, 0};
        float4 acc2 = {0, 0, 0, 0}, acc3 = {0, 0, 0, 0};
#pragma unroll 4
        for (int k4 = 0; k4 < 32; ++k4) {
            float4 a0 = p0[k4], a1 = p1[k4], a2 = p2[k4], a3 = p3[k4];
            float4 w0 = sW4[(k4 * 4 + 0) * 16 + tx];
            float4 w1 = sW4[(k4 * 4 + 1) * 16 + tx];
            float4 w2 = sW4[(k4 * 4 + 2) * 16 + tx];
            float4 w3 = sW4[(k4 * 4 + 3) * 16 + tx];
            fma4(acc0, a0.x, w0); fma4(acc0, a0.y, w1); fma4(acc0, a0.z, w2); fma4(acc0, a0.w, w3);
            fma4(acc1, a1.x, w0); fma4(acc1, a1.y, w1); fma4(acc1, a1.z, w2); fma4(acc1, a1.w, w3);
            fma4(acc2, a2.x, w0); fma4(acc2, a2.y, w1); fma4(acc2, a2.z, w2); fma4(acc2, a2.w, w3);
            fma4(acc3, a3.x, w0); fma4(acc3, a3.y, w1); fma4(acc3, a3.z, w2); fma4(acc3, a3.w, w3);
        }
        float4 accs[4] = {acc0, acc1, acc2, acc3};
#pragma unroll
        for (int j = 0; j < 4; ++j) {
            if (vld[j]) {
                float d = dinv[r[j]];
                ushort4 o;
                o.x = f2bf(d * accs[j].x);
                o.y = f2bf(d * accs[j].y);
                o.z = f2bf(d * accs[j].z);
                o.w = f2bf(d * accs[j].w);
                *(ushort4*)(u + (size_t)r[j] * 128 + c0 + tx * 4) = o;
            }
        }
    }
}

// ---------------- aggregate: h[i] = relu(dinv[i]*(sum_in u[src] + u[i]) + b) ----------------
__global__ __launch_bounds__(256) void k_agg(const unsigned int* __restrict__ u,
                                             const int* __restrict__ offs,
                                             const int* __restrict__ csr,
                                             const float* __restrict__ dinv,
                                             const float* __restrict__ bias,
                                             float* __restrict__ hout) {
    int wid = threadIdx.x >> 6;
    int lane = threadIdx.x & 63;
    int node = blockIdx.x * 4 + wid;
    if (node >= N_NODES) return;
    unsigned int self = u[(size_t)node * 64 + lane];
    float a0x = bf_lo(self), a0y = bf_hi(self);
    float a1x = 0.f, a1y = 0.f, a2x = 0.f, a2y = 0.f, a3x = 0.f, a3y = 0.f;
    int p = offs[node], e = offs[node + 1];
    for (; p + 3 < e; p += 4) {
        int s0 = csr[p], s1 = csr[p + 1], s2 = csr[p + 2], s3 = csr[p + 3];
        unsigned int v0 = u[(size_t)s0 * 64 + lane];
        unsigned int v1 = u[(size_t)s1 * 64 + lane];
        unsigned int v2 = u[(size_t)s2 * 64 + lane];
        unsigned int v3 = u[(size_t)s3 * 64 + lane];
        a0x += bf_lo(v0); a0y += bf_hi(v0);
        a1x += bf_lo(v1); a1y += bf_hi(v1);
        a2x += bf_lo(v2); a2y += bf_hi(v2);
        a3x += bf_lo(v3); a3y += bf_hi(v3);
    }
    for (; p < e; ++p) {
        unsigned int v0 = u[(size_t)csr[p] * 64 + lane];
        a0x += bf_lo(v0); a0y += bf_hi(v0);
    }
    float d = dinv[node];
    float2 b = ((const float2*)bias)[lane];
    float sx = a0x + a1x + a2x + a3x;
    float sy = a0y + a1y + a2y + a3y;
    float r0 = fmaxf(d * sx + b.x, 0.f);
    float r1 = fmaxf(d * sy + b.y, 0.f);
    ((float2*)hout)[(size_t)node * 64 + lane] = make_float2(r0, r1);
}

// ---------------- pool (batch sorted) + linear head ----------------
__global__ __launch_bounds__(128) void k_pool(const float* __restrict__ h,
                                              const int* __restrict__ batch,
                                              const float* __restrict__ Wl,
                                              const float* __restrict__ bl,
                                              float* __restrict__ out) {
    int g = blockIdx.x;
    int c = threadIdx.x;
    __shared__ int sb[2];
    if (c < 2) {
        int tgt = g + c;
        int lo = 0, hi = N_NODES;
        while (lo < hi) { int m = (lo + hi) >> 1; if (batch[m] < tgt) lo = m + 1; else hi = m; }
        sb[c] = lo;
    }
    __syncthreads();
    int s0 = sb[0], s1 = sb[1];
    float sum = 0.f;
    for (int i = s0; i < s1; ++i) sum += h[(size_t)i * 128 + c];
    float cnt = (float)(s1 - s0);
    float pooled = sum / fmaxf(cnt, 1.0f);
    __shared__ float red[128];
    float w0 = Wl[c * 2 + 0], w1 = Wl[c * 2 + 1];
    red[c] = pooled * w0;
    __syncthreads();
    for (int st = 64; st > 0; st >>= 1) { if (c < st) red[c] += red[c + st]; __syncthreads(); }
    if (c == 0) out[g * 2 + 0] = red[0] + bl[0];
    __syncthreads();
    red[c] = pooled * w1;
    __syncthreads();
    for (int st = 64; st > 0; st >>= 1) { if (c < st) red[c] += red[c + st]; __syncthreads(); }
    if (c == 0) out[g * 2 + 1] = red[0] + bl[1];
}

extern "C" void kernel_launch(void* const* d_in, const int* in_sizes, int n_in,
                              void* d_out, int out_size, void* d_ws, size_t ws_size,
                              hipStream_t stream) {
    const float* x  = (const float*)d_in[0];
    const int* ei   = (const int*)d_in[1];
    const int* batch = (const int*)d_in[2];
    const float* W1 = (const float*)d_in[3];
    const float* b1 = (const float*)d_in[4];
    const float* W2 = (const float*)d_in[5];
    const float* b2 = (const float*)d_in[6];
    const float* Wl = (const float*)d_in[7];
    const float* bl = (const float*)d_in[8];
    float* out = (float*)d_out;
    const int* src = ei;
    const int* dst = ei + N_EDGES;

    char* ws = (char*)d_ws;
    size_t o = 0;
    auto alloc = [&](size_t bytes) -> void* {
        o = (o + 255) & ~(size_t)255;
        void* p = ws + o;
        o += bytes;
        return p;
    };
    int* bcount = (int*)alloc((size_t)NBUCK * 4);
    int* bbase  = (int*)alloc((size_t)NBUCK * 4);
    int* bcur   = (int*)alloc((size_t)NBUCK * 4);
    int* wsum   = (int*)alloc((size_t)NBUCK * 4);
    int* wbase  = (int*)alloc((size_t)NBUCK * 4);
    int* deg    = (int*)alloc((size_t)N_NODES * 4);
    float* dinv = (float*)alloc((size_t)N_NODES * 4);
    int* offs   = (int*)alloc((size_t)(N_NODES + 1) * 4);
    uint2* pairs = (uint2*)alloc((size_t)N_EDGES * 8);
    int* csr    = (int*)alloc((size_t)N_EDGES * 4);
    unsigned short* u = (unsigned short*)alloc((size_t)N_NODES * 128 * 2);  // bf16
    float* h    = (float*)alloc((size_t)N_NODES * 128 * 4);

    hipMemsetAsync(bcount, 0, (size_t)NBUCK * 4, stream);
    k_hist<<<256, 256, 0, stream>>>(dst, bcount);
    k_scan391<<<1, 512, 0, stream>>>(bcount, bbase, bcur, nullptr);
    k_bucket<<<(N_EDGES + CHUNK - 1) / CHUNK, 256, 0, stream>>>(src, dst, bcur, pairs);
    k_bdeg<<<NBUCK, 256, 0, stream>>>(pairs, bbase, bcount, deg, wsum);
    k_dinv<<<(N_NODES + 255) / 256, 256, 0, stream>>>(deg, dinv);
    k_scan391<<<1, 512, 0, stream>>>(wsum, wbase, nullptr, &offs[N_NODES]);
    k_bfill<<<NBUCK, 256, 0, stream>>>(pairs, bbase, bcount, deg, wbase, offs, csr);

    k_gemm_scale<<<1024, 256, 0, stream>>>(x, W1, dinv, u);
    k_agg<<<(N_NODES + 3) / 4, 256, 0, stream>>>((const unsigned int*)u, offs, csr, dinv, b1, h);
    k_gemm_scale<<<1024, 256, 0, stream>>>(h, W2, dinv, u);
    k_agg<<<(N_NODES + 3) / 4, 256, 0, stream>>>((const unsigned int*)u, offs, csr, dinv, b2, h);

    k_pool<<<N_GRAPHS, 128, 0, stream>>>(h, batch, Wl, bl, out);
}

// Round 4
// 402.158 us; speedup vs baseline: 2.0241x; 1.1598x over previous
//
#include <hip/hip_runtime.h>
#include <hip/hip_bf16.h>

#define N_NODES 100000
#define N_EDGES 1600000
#define FEAT 128
#define N_GRAPHS 1024
#define NBUCK 391   // ceil(N_NODES/256) windows of 256 nodes (bucket = dst >> 8)
#define CHUNK 4096  // edges per k_bucket block

typedef short short8 __attribute__((ext_vector_type(8)));
typedef float float4v __attribute__((ext_vector_type(4)));

static __device__ inline unsigned short f2bf(float f) {
    __hip_bfloat16 b = __float2bfloat16(f);
    unsigned short r;
    __builtin_memcpy(&r, &b, 2);
    return r;
}
static __device__ inline float bf_lo(unsigned int v) { return __uint_as_float(v << 16); }
static __device__ inline float bf_hi(unsigned int v) { return __uint_as_float(v & 0xFFFF0000u); }

// ---------------- bucket histogram (LDS-staged) ----------------
__global__ __launch_bounds__(256) void k_hist(const int* __restrict__ dst,
                                              int* __restrict__ bcount) {
    __shared__ int h[NBUCK];
    for (int i = threadIdx.x; i < NBUCK; i += 256) h[i] = 0;
    __syncthreads();
    for (int e = blockIdx.x * 256 + threadIdx.x; e < N_EDGES; e += gridDim.x * 256)
        atomicAdd(&h[dst[e] >> 8], 1);
    __syncthreads();
    for (int i = threadIdx.x; i < NBUCK; i += 256) {
        int c = h[i];
        if (c) atomicAdd(&bcount[i], c);
    }
}

// ---------------- exclusive scan of 391 values (single block) ----------------
__global__ __launch_bounds__(512) void k_scan391(const int* __restrict__ in,
                                                 int* __restrict__ base,
                                                 int* __restrict__ cur,
                                                 int* __restrict__ tail) {
    int t = threadIdx.x;
    int v = (t < NBUCK) ? in[t] : 0;
    int lane = t & 63, wid = t >> 6;
    int s = v;
#pragma unroll
    for (int d = 1; d < 64; d <<= 1) { int n = __shfl_up(s, d); if (lane >= d) s += n; }
    __shared__ int ws[8];
    if (lane == 63) ws[wid] = s;
    __syncthreads();
    if (t < 8) {
        int x = ws[t];
#pragma unroll
        for (int d = 1; d < 8; d <<= 1) { int n = __shfl_up(x, d); if ((int)t >= d) x += n; }
        ws[t] = x;
    }
    __syncthreads();
    int excl = s - v + (wid ? ws[wid - 1] : 0);
    if (t < NBUCK) {
        base[t] = excl;
        if (cur) cur[t] = excl;
    }
    if (t == 0 && tail) tail[0] = N_EDGES;
}

// ---------------- bin edges into bucket runs (block counting-sort) ----------------
__global__ __launch_bounds__(256) void k_bucket(const int* __restrict__ src,
                                                const int* __restrict__ dst,
                                                int* __restrict__ bcur,
                                                uint2* __restrict__ pairs) {
    __shared__ int cnt[NBUCK];
    __shared__ int basebuf[NBUCK];
    int t = threadIdx.x;
    int e0 = blockIdx.x * CHUNK;
    for (int i = t; i < NBUCK; i += 256) cnt[i] = 0;
    __syncthreads();
    int es[16], ed[16];
#pragma unroll
    for (int j = 0; j < 16; ++j) {
        int e = e0 + j * 256 + t;
        if (e < N_EDGES) {
            es[j] = src[e];
            ed[j] = dst[e];
            atomicAdd(&cnt[ed[j] >> 8], 1);
        } else ed[j] = -1;
    }
    __syncthreads();
    for (int i = t; i < NBUCK; i += 256) {
        int c = cnt[i];
        basebuf[i] = c ? atomicAdd(&bcur[i], c) : 0;
        cnt[i] = 0;
    }
    __syncthreads();
#pragma unroll
    for (int j = 0; j < 16; ++j) {
        if (ed[j] >= 0) {
            int b = ed[j] >> 8;
            int p = basebuf[b] + atomicAdd(&cnt[b], 1);
            pairs[p] = make_uint2((unsigned)es[j], (unsigned)ed[j]);
        }
    }
}

// ---------------- per-bucket degree via LDS atomics ----------------
__global__ __launch_bounds__(256) void k_bdeg(const uint2* __restrict__ pairs,
                                              const int* __restrict__ bbase,
                                              const int* __restrict__ bcount,
                                              int* __restrict__ deg,
                                              int* __restrict__ wsum) {
    __shared__ int d[256];
    __shared__ int wr[4];
    int b = blockIdx.x, t = threadIdx.x;
    d[t] = 0;
    __syncthreads();
    int s0 = bbase[b], n = bcount[b];
    for (int i = t; i < n; i += 256) atomicAdd(&d[pairs[s0 + i].y & 255], 1);
    __syncthreads();
    int node = b * 256 + t;
    int v = d[t];
    if (node < N_NODES) deg[node] = v;
#pragma unroll
    for (int dd = 32; dd > 0; dd >>= 1) v += __shfl_down(v, dd);
    if ((t & 63) == 0) wr[t >> 6] = v;
    __syncthreads();
    if (t == 0) wsum[b] = wr[0] + wr[1] + wr[2] + wr[3];
}

__global__ void k_dinv(const int* __restrict__ deg, float* __restrict__ dinv) {
    int i = blockIdx.x * 256 + threadIdx.x;
    if (i < N_NODES) dinv[i] = rsqrtf((float)(deg[i] + 1));  // +1 self-loop
}

// ---------------- per-bucket CSR fill (L2-local scatter) ----------------
__global__ __launch_bounds__(256) void k_bfill(const uint2* __restrict__ pairs,
                                               const int* __restrict__ bbase,
                                               const int* __restrict__ bcount,
                                               const int* __restrict__ deg,
                                               const int* __restrict__ wbase,
                                               int* __restrict__ offs,
                                               int* __restrict__ csr) {
    __shared__ int lcur[256];
    __shared__ int ws[4];
    int b = blockIdx.x, t = threadIdx.x;
    int node = b * 256 + t;
    int dv = (node < N_NODES) ? deg[node] : 0;
    int lane = t & 63, wid = t >> 6;
    int s = dv;
#pragma unroll
    for (int d = 1; d < 64; d <<= 1) { int n = __shfl_up(s, d); if (lane >= d) s += n; }
    if (lane == 63) ws[wid] = s;
    __syncthreads();
    if (t < 4) {
        int x = ws[t];
#pragma unroll
        for (int d = 1; d < 4; d <<= 1) { int n = __shfl_up(x, d); if ((int)t >= d) x += n; }
        ws[t] = x;
    }
    __syncthreads();
    int excl = s - dv + (wid ? ws[wid - 1] : 0) + wbase[b];
    if (node < N_NODES) offs[node] = excl;
    lcur[t] = excl;
    __syncthreads();
    int s0 = bbase[b], n = bcount[b];
    for (int i = t; i < n; i += 256) {
        uint2 pr = pairs[s0 + i];
        int p = atomicAdd(&lcur[pr.y & 255], 1);
        csr[p] = (int)pr.x;
    }
}

// ---------------- W prep: split fp32 W[128x128] into hi/lo bf16, transposed+swizzled ----------
// Element (k,n) -> index n*128 + ((k&7) | 8*(((k>>3) ^ n) & 15)); wp[0..16383]=hi, [16384..]=lo.
__global__ __launch_bounds__(256) void k_prepW(const float* __restrict__ W,
                                               unsigned short* __restrict__ wp) {
    int t = blockIdx.x * 256 + threadIdx.x;
    if (t >= 16384) return;
    int k = t >> 7, n = t & 127;
    float w = W[k * 128 + n];
    unsigned ub = __float_as_uint(w);
    unsigned short hi = (unsigned short)(ub >> 16);  // truncation split
    float hif = __uint_as_float(ub & 0xFFFF0000u);
    unsigned short lo = f2bf(w - hif);               // RNE residual
    int sidx = n * 128 + ((k & 7) | (8 * (((k >> 3) ^ n) & 15)));
    wp[sidx] = hi;
    wp[16384 + sidx] = lo;
}

// ---------------- MFMA GEMM: u = bf16( dinv .* (inp @ W) ) ----------------
// 64 rows/block, 4 waves x 16 rows, all 128 cols. W (hi+lo) in 64KB LDS.
// Split-bf16: inp ~ Ah+Al, W ~ Wh+Wl; acc += Ah*Wh + Al*Wh + Ah*Wl.
__global__ __launch_bounds__(256) void k_gemm_mfma(const float* __restrict__ inp,
                                                   const unsigned short* __restrict__ wp,
                                                   const float* __restrict__ dinv,
                                                   unsigned short* __restrict__ u) {
    __shared__ unsigned short sW[32768];  // 64 KB: [0..16383]=hi, [16384..]=lo (swizzled)
    {
        float4* d4 = (float4*)sW;
        const float4* s4 = (const float4*)wp;
#pragma unroll
        for (int i = 0; i < 16; ++i) d4[threadIdx.x + 256 * i] = s4[threadIdx.x + 256 * i];
    }
    __syncthreads();
    const int t = threadIdx.x;
    const int wv = t >> 6, L = t & 63;
    const int m = L & 15, q = L >> 4;
    const int r0 = blockIdx.x * 64 + wv * 16;
    int arow = r0 + m;
    if (arow >= N_NODES) arow = N_NODES - 1;
    const float4* ap = (const float4*)(inp + (size_t)arow * 128);
    float4v acc[8];
#pragma unroll
    for (int c = 0; c < 8; ++c) acc[c] = (float4v){0.f, 0.f, 0.f, 0.f};

#pragma unroll
    for (int k0 = 0; k0 < 128; k0 += 32) {
        float4 f0 = ap[(k0 >> 2) + 2 * q];
        float4 f1 = ap[(k0 >> 2) + 2 * q + 1];
        float fa[8] = {f0.x, f0.y, f0.z, f0.w, f1.x, f1.y, f1.z, f1.w};
        short8 ah, al;
#pragma unroll
        for (int j = 0; j < 8; ++j) {
            unsigned ub = __float_as_uint(fa[j]);
            ah[j] = (short)(ub >> 16);
            float hif = __uint_as_float(ub & 0xFFFF0000u);
            al[j] = (short)f2bf(fa[j] - hif);
        }
        const int b = (k0 >> 3) + q;
#pragma unroll
        for (int c = 0; c < 8; ++c) {
            int ng = c * 16 + m;
            int elem = ng * 128 + 8 * ((b ^ ng) & 15);
            short8 bh = *(const short8*)&sW[elem];
            short8 bl = *(const short8*)&sW[16384 + elem];
            acc[c] = __builtin_amdgcn_mfma_f32_16x16x32_bf16(ah, bh, acc[c], 0, 0, 0);
            acc[c] = __builtin_amdgcn_mfma_f32_16x16x32_bf16(al, bh, acc[c], 0, 0, 0);
            acc[c] = __builtin_amdgcn_mfma_f32_16x16x32_bf16(ah, bl, acc[c], 0, 0, 0);
        }
    }
    // epilogue: D[row=(q*4+r)][col=c*16+m]
#pragma unroll
    for (int r = 0; r < 4; ++r) {
        int row = r0 + 4 * q + r;
        if (row < N_NODES) {
            float dv = dinv[row];
            unsigned short* up = u + (size_t)row * 128 + m;
#pragma unroll
            for (int c = 0; c < 8; ++c) up[c * 16] = f2bf(dv * acc[c][r]);
        }
    }
}

// ---------------- aggregate: h[i] = relu(dinv[i]*(sum_in u[src] + u[i]) + b) ----------------
__global__ __launch_bounds__(256) void k_agg(const unsigned int* __restrict__ u,
                                             const int* __restrict__ offs,
                                             const int* __restrict__ csr,
                                             const float* __restrict__ dinv,
                                             const float* __restrict__ bias,
                                             float* __restrict__ hout) {
    int wid = threadIdx.x >> 6;
    int lane = threadIdx.x & 63;
    int node = blockIdx.x * 4 + wid;
    if (node >= N_NODES) return;
    unsigned int self = u[(size_t)node * 64 + lane];
    float a0x = bf_lo(self), a0y = bf_hi(self);
    float a1x = 0.f, a1y = 0.f, a2x = 0.f, a2y = 0.f, a3x = 0.f, a3y = 0.f;
    int p = offs[node], e = offs[node + 1];
    for (; p + 3 < e; p += 4) {
        int s0 = csr[p], s1 = csr[p + 1], s2 = csr[p + 2], s3 = csr[p + 3];
        unsigned int v0 = u[(size_t)s0 * 64 + lane];
        unsigned int v1 = u[(size_t)s1 * 64 + lane];
        unsigned int v2 = u[(size_t)s2 * 64 + lane];
        unsigned int v3 = u[(size_t)s3 * 64 + lane];
        a0x += bf_lo(v0); a0y += bf_hi(v0);
        a1x += bf_lo(v1); a1y += bf_hi(v1);
        a2x += bf_lo(v2); a2y += bf_hi(v2);
        a3x += bf_lo(v3); a3y += bf_hi(v3);
    }
    for (; p < e; ++p) {
        unsigned int v0 = u[(size_t)csr[p] * 64 + lane];
        a0x += bf_lo(v0); a0y += bf_hi(v0);
    }
    float d = dinv[node];
    float2 b = ((const float2*)bias)[lane];
    float sx = a0x + a1x + a2x + a3x;
    float sy = a0y + a1y + a2y + a3y;
    float r0 = fmaxf(d * sx + b.x, 0.f);
    float r1 = fmaxf(d * sy + b.y, 0.f);
    ((float2*)hout)[(size_t)node * 64 + lane] = make_float2(r0, r1);
}

// ---------------- pool (batch sorted) + linear head ----------------
__global__ __launch_bounds__(128) void k_pool(const float* __restrict__ h,
                                              const int* __restrict__ batch,
                                              const float* __restrict__ Wl,
                                              const float* __restrict__ bl,
                                              float* __restrict__ out) {
    int g = blockIdx.x;
    int c = threadIdx.x;
    __shared__ int sb[2];
    if (c < 2) {
        int tgt = g + c;
        int lo = 0, hi = N_NODES;
        while (lo < hi) { int m = (lo + hi) >> 1; if (batch[m] < tgt) lo = m + 1; else hi = m; }
        sb[c] = lo;
    }
    __syncthreads();
    int s0 = sb[0], s1 = sb[1];
    float sum = 0.f;
    for (int i = s0; i < s1; ++i) sum += h[(size_t)i * 128 + c];
    float cnt = (float)(s1 - s0);
    float pooled = sum / fmaxf(cnt, 1.0f);
    __shared__ float red[128];
    float w0 = Wl[c * 2 + 0], w1 = Wl[c * 2 + 1];
    red[c] = pooled * w0;
    __syncthreads();
    for (int st = 64; st > 0; st >>= 1) { if (c < st) red[c] += red[c + st]; __syncthreads(); }
    if (c == 0) out[g * 2 + 0] = red[0] + bl[0];
    __syncthreads();
    red[c] = pooled * w1;
    __syncthreads();
    for (int st = 64; st > 0; st >>= 1) { if (c < st) red[c] += red[c + st]; __syncthreads(); }
    if (c == 0) out[g * 2 + 1] = red[0] + bl[1];
}

extern "C" void kernel_launch(void* const* d_in, const int* in_sizes, int n_in,
                              void* d_out, int out_size, void* d_ws, size_t ws_size,
                              hipStream_t stream) {
    const float* x  = (const float*)d_in[0];
    const int* ei   = (const int*)d_in[1];
    const int* batch = (const int*)d_in[2];
    const float* W1 = (const float*)d_in[3];
    const float* b1 = (const float*)d_in[4];
    const float* W2 = (const float*)d_in[5];
    const float* b2 = (const float*)d_in[6];
    const float* Wl = (const float*)d_in[7];
    const float* bl = (const float*)d_in[8];
    float* out = (float*)d_out;
    const int* src = ei;
    const int* dst = ei + N_EDGES;

    char* ws = (char*)d_ws;
    size_t o = 0;
    auto alloc = [&](size_t bytes) -> void* {
        o = (o + 255) & ~(size_t)255;
        void* p = ws + o;
        o += bytes;
        return p;
    };
    int* bcount = (int*)alloc((size_t)NBUCK * 4);
    int* bbase  = (int*)alloc((size_t)NBUCK * 4);
    int* bcur   = (int*)alloc((size_t)NBUCK * 4);
    int* wsum   = (int*)alloc((size_t)NBUCK * 4);
    int* wbase  = (int*)alloc((size_t)NBUCK * 4);
    int* deg    = (int*)alloc((size_t)N_NODES * 4);
    float* dinv = (float*)alloc((size_t)N_NODES * 4);
    int* offs   = (int*)alloc((size_t)(N_NODES + 1) * 4);
    unsigned short* wp1 = (unsigned short*)alloc(65536);
    unsigned short* wp2 = (unsigned short*)alloc(65536);
    uint2* pairs = (uint2*)alloc((size_t)N_EDGES * 8);
    int* csr    = (int*)alloc((size_t)N_EDGES * 4);
    unsigned short* u = (unsigned short*)alloc((size_t)N_NODES * 128 * 2);  // bf16
    float* h    = (float*)alloc((size_t)N_NODES * 128 * 4);

    hipMemsetAsync(bcount, 0, (size_t)NBUCK * 4, stream);
    k_prepW<<<64, 256, 0, stream>>>(W1, wp1);
    k_prepW<<<64, 256, 0, stream>>>(W2, wp2);
    k_hist<<<256, 256, 0, stream>>>(dst, bcount);
    k_scan391<<<1, 512, 0, stream>>>(bcount, bbase, bcur, nullptr);
    k_bucket<<<(N_EDGES + CHUNK - 1) / CHUNK, 256, 0, stream>>>(src, dst, bcur, pairs);
    k_bdeg<<<NBUCK, 256, 0, stream>>>(pairs, bbase, bcount, deg, wsum);
    k_dinv<<<(N_NODES + 255) / 256, 256, 0, stream>>>(deg, dinv);
    k_scan391<<<1, 512, 0, stream>>>(wsum, wbase, nullptr, &offs[N_NODES]);
    k_bfill<<<NBUCK, 256, 0, stream>>>(pairs, bbase, bcount, deg, wbase, offs, csr);

    const int gemmGrid = (N_NODES + 63) / 64;  // 1563
    k_gemm_mfma<<<gemmGrid, 256, 0, stream>>>(x, wp1, dinv, u);
    k_agg<<<(N_NODES + 3) / 4, 256, 0, stream>>>((const unsigned int*)u, offs, csr, dinv, b1, h);
    k_gemm_mfma<<<gemmGrid, 256, 0, stream>>>(h, wp2, dinv, u);
    k_agg<<<(N_NODES + 3) / 4, 256, 0, stream>>>((const unsigned int*)u, offs, csr, dinv, b2, h);

    k_pool<<<N_GRAPHS, 128, 0, stream>>>(h, batch, Wl, bl, out);
}

// Round 5
// 383.046 us; speedup vs baseline: 2.1251x; 1.0499x over previous
//
#include <hip/hip_runtime.h>
#include <hip/hip_bf16.h>

#define N_NODES 100000
#define N_EDGES 1600000
#define FEAT 128
#define N_GRAPHS 1024
#define NBUCK 391   // ceil(N_NODES/256) windows of 256 nodes (bucket = dst >> 8)
#define CHUNK 4096  // edges per k_bucket block

typedef short short8 __attribute__((ext_vector_type(8)));
typedef float float4v __attribute__((ext_vector_type(4)));

static __device__ inline unsigned short f2bf(float f) {
    __hip_bfloat16 b = __float2bfloat16(f);
    unsigned short r;
    __builtin_memcpy(&r, &b, 2);
    return r;
}
static __device__ inline float bf_lo(unsigned int v) { return __uint_as_float(v << 16); }
static __device__ inline float bf_hi(unsigned int v) { return __uint_as_float(v & 0xFFFF0000u); }

// ---------------- bucket histogram (LDS-staged) ----------------
__global__ __launch_bounds__(256) void k_hist(const int* __restrict__ dst,
                                              int* __restrict__ bcount) {
    __shared__ int h[NBUCK];
    for (int i = threadIdx.x; i < NBUCK; i += 256) h[i] = 0;
    __syncthreads();
    for (int e = blockIdx.x * 256 + threadIdx.x; e < N_EDGES; e += gridDim.x * 256)
        atomicAdd(&h[dst[e] >> 8], 1);
    __syncthreads();
    for (int i = threadIdx.x; i < NBUCK; i += 256) {
        int c = h[i];
        if (c) atomicAdd(&bcount[i], c);
    }
}

// ---------------- exclusive scan of 391 values (single block) ----------------
__global__ __launch_bounds__(512) void k_scan391(const int* __restrict__ in,
                                                 int* __restrict__ base,
                                                 int* __restrict__ cur,
                                                 int* __restrict__ tail) {
    int t = threadIdx.x;
    int v = (t < NBUCK) ? in[t] : 0;
    int lane = t & 63, wid = t >> 6;
    int s = v;
#pragma unroll
    for (int d = 1; d < 64; d <<= 1) { int n = __shfl_up(s, d); if (lane >= d) s += n; }
    __shared__ int ws[8];
    if (lane == 63) ws[wid] = s;
    __syncthreads();
    if (t < 8) {
        int x = ws[t];
#pragma unroll
        for (int d = 1; d < 8; d <<= 1) { int n = __shfl_up(x, d); if ((int)t >= d) x += n; }
        ws[t] = x;
    }
    __syncthreads();
    int excl = s - v + (wid ? ws[wid - 1] : 0);
    if (t < NBUCK) {
        base[t] = excl;
        if (cur) cur[t] = excl;
    }
    if (t == 0 && tail) tail[0] = N_EDGES;
}

// ---------------- bin edges into bucket runs (block counting-sort) ----------------
__global__ __launch_bounds__(256) void k_bucket(const int* __restrict__ src,
                                                const int* __restrict__ dst,
                                                int* __restrict__ bcur,
                                                uint2* __restrict__ pairs) {
    __shared__ int cnt[NBUCK];
    __shared__ int basebuf[NBUCK];
    int t = threadIdx.x;
    int e0 = blockIdx.x * CHUNK;
    for (int i = t; i < NBUCK; i += 256) cnt[i] = 0;
    __syncthreads();
    int es[16], ed[16];
#pragma unroll
    for (int j = 0; j < 16; ++j) {
        int e = e0 + j * 256 + t;
        if (e < N_EDGES) {
            es[j] = src[e];
            ed[j] = dst[e];
            atomicAdd(&cnt[ed[j] >> 8], 1);
        } else ed[j] = -1;
    }
    __syncthreads();
    for (int i = t; i < NBUCK; i += 256) {
        int c = cnt[i];
        basebuf[i] = c ? atomicAdd(&bcur[i], c) : 0;
        cnt[i] = 0;
    }
    __syncthreads();
#pragma unroll
    for (int j = 0; j < 16; ++j) {
        if (ed[j] >= 0) {
            int b = ed[j] >> 8;
            int p = basebuf[b] + atomicAdd(&cnt[b], 1);
            pairs[p] = make_uint2((unsigned)es[j], (unsigned)ed[j]);
        }
    }
}

// ---------------- per-bucket degree via LDS atomics (+ fused dinv) ----------------
__global__ __launch_bounds__(256) void k_bdeg(const uint2* __restrict__ pairs,
                                              const int* __restrict__ bbase,
                                              const int* __restrict__ bcount,
                                              int* __restrict__ deg,
                                              float* __restrict__ dinv,
                                              int* __restrict__ wsum) {
    __shared__ int d[256];
    __shared__ int wr[4];
    int b = blockIdx.x, t = threadIdx.x;
    d[t] = 0;
    __syncthreads();
    int s0 = bbase[b], n = bcount[b];
    for (int i = t; i < n; i += 256) atomicAdd(&d[pairs[s0 + i].y & 255], 1);
    __syncthreads();
    int node = b * 256 + t;
    int v = d[t];
    if (node < N_NODES) {
        deg[node] = v;
        dinv[node] = rsqrtf((float)(v + 1));  // +1 self-loop
    }
#pragma unroll
    for (int dd = 32; dd > 0; dd >>= 1) v += __shfl_down(v, dd);
    if ((t & 63) == 0) wr[t >> 6] = v;
    __syncthreads();
    if (t == 0) wsum[b] = wr[0] + wr[1] + wr[2] + wr[3];
}

// ---------------- per-bucket CSR fill (L2-local scatter) ----------------
__global__ __launch_bounds__(256) void k_bfill(const uint2* __restrict__ pairs,
                                               const int* __restrict__ bbase,
                                               const int* __restrict__ bcount,
                                               const int* __restrict__ deg,
                                               const int* __restrict__ wbase,
                                               int* __restrict__ offs,
                                               int* __restrict__ csr) {
    __shared__ int lcur[256];
    __shared__ int ws[4];
    int b = blockIdx.x, t = threadIdx.x;
    int node = b * 256 + t;
    int dv = (node < N_NODES) ? deg[node] : 0;
    int lane = t & 63, wid = t >> 6;
    int s = dv;
#pragma unroll
    for (int d = 1; d < 64; d <<= 1) { int n = __shfl_up(s, d); if (lane >= d) s += n; }
    if (lane == 63) ws[wid] = s;
    __syncthreads();
    if (t < 4) {
        int x = ws[t];
#pragma unroll
        for (int d = 1; d < 4; d <<= 1) { int n = __shfl_up(x, d); if ((int)t >= d) x += n; }
        ws[t] = x;
    }
    __syncthreads();
    int excl = s - dv + (wid ? ws[wid - 1] : 0) + wbase[b];
    if (node < N_NODES) offs[node] = excl;
    lcur[t] = excl;
    __syncthreads();
    int s0 = bbase[b], n = bcount[b];
    for (int i = t; i < n; i += 256) {
        uint2 pr = pairs[s0 + i];
        int p = atomicAdd(&lcur[pr.y & 255], 1);
        csr[p] = (int)pr.x;
    }
}

// ---------------- W prep: split fp32 W[128x128] into hi/lo bf16, transposed+swizzled ----------
__global__ __launch_bounds__(256) void k_prepW(const float* __restrict__ W,
                                               unsigned short* __restrict__ wp) {
    int t = blockIdx.x * 256 + threadIdx.x;
    if (t >= 16384) return;
    int k = t >> 7, n = t & 127;
    float w = W[k * 128 + n];
    unsigned ub = __float_as_uint(w);
    unsigned short hi = (unsigned short)(ub >> 16);  // truncation split
    float hif = __uint_as_float(ub & 0xFFFF0000u);
    unsigned short lo = f2bf(w - hif);               // RNE residual
    int sidx = n * 128 + ((k & 7) | (8 * (((k >> 3) ^ n) & 15)));
    wp[sidx] = hi;
    wp[16384 + sidx] = lo;
}

// ---------------- MFMA GEMM: u = bf16( dinv .* (inp @ W) ) ----------------
__global__ __launch_bounds__(256) void k_gemm_mfma(const float* __restrict__ inp,
                                                   const unsigned short* __restrict__ wp,
                                                   const float* __restrict__ dinv,
                                                   unsigned short* __restrict__ u) {
    __shared__ unsigned short sW[32768];  // 64 KB: [0..16383]=hi, [16384..]=lo (swizzled)
    {
        float4* d4 = (float4*)sW;
        const float4* s4 = (const float4*)wp;
#pragma unroll
        for (int i = 0; i < 16; ++i) d4[threadIdx.x + 256 * i] = s4[threadIdx.x + 256 * i];
    }
    __syncthreads();
    const int t = threadIdx.x;
    const int wv = t >> 6, L = t & 63;
    const int m = L & 15, q = L >> 4;
    const int r0 = blockIdx.x * 64 + wv * 16;
    int arow = r0 + m;
    if (arow >= N_NODES) arow = N_NODES - 1;
    const float4* ap = (const float4*)(inp + (size_t)arow * 128);
    float4v acc[8];
#pragma unroll
    for (int c = 0; c < 8; ++c) acc[c] = (float4v){0.f, 0.f, 0.f, 0.f};

#pragma unroll
    for (int k0 = 0; k0 < 128; k0 += 32) {
        float4 f0 = ap[(k0 >> 2) + 2 * q];
        float4 f1 = ap[(k0 >> 2) + 2 * q + 1];
        float fa[8] = {f0.x, f0.y, f0.z, f0.w, f1.x, f1.y, f1.z, f1.w};
        short8 ah, al;
#pragma unroll
        for (int j = 0; j < 8; ++j) {
            unsigned ub = __float_as_uint(fa[j]);
            ah[j] = (short)(ub >> 16);
            float hif = __uint_as_float(ub & 0xFFFF0000u);
            al[j] = (short)f2bf(fa[j] - hif);
        }
        const int b = (k0 >> 3) + q;
#pragma unroll
        for (int c = 0; c < 8; ++c) {
            int ng = c * 16 + m;
            int elem = ng * 128 + 8 * ((b ^ ng) & 15);
            short8 bh = *(const short8*)&sW[elem];
            short8 bl = *(const short8*)&sW[16384 + elem];
            acc[c] = __builtin_amdgcn_mfma_f32_16x16x32_bf16(ah, bh, acc[c], 0, 0, 0);
            acc[c] = __builtin_amdgcn_mfma_f32_16x16x32_bf16(al, bh, acc[c], 0, 0, 0);
            acc[c] = __builtin_amdgcn_mfma_f32_16x16x32_bf16(ah, bl, acc[c], 0, 0, 0);
        }
    }
#pragma unroll
    for (int r = 0; r < 4; ++r) {
        int row = r0 + 4 * q + r;
        if (row < N_NODES) {
            float dv = dinv[row];
            unsigned short* up = u + (size_t)row * 128 + m;
#pragma unroll
            for (int c = 0; c < 8; ++c) up[c * 16] = f2bf(dv * acc[c][r]);
        }
    }
}

// ---------------- aggregate: h[i] = relu(dinv[i]*(sum_in u[src] + u[i]) + b) ----------------
// one wave per node; lane = 2 cols. Unroll-8 masked loop: uniform trip count, no serial
// tail, 8+ loads in flight (latency-bound fix; masked lanes re-read clamped idx = L2 hit).
__global__ __launch_bounds__(256) void k_agg(const unsigned int* __restrict__ u,
                                             const int* __restrict__ offs,
                                             const int* __restrict__ csr,
                                             const float* __restrict__ dinv,
                                             const float* __restrict__ bias,
                                             float* __restrict__ hout) {
    int wid = threadIdx.x >> 6;
    int lane = threadIdx.x & 63;
    int node = blockIdx.x * 4 + wid;
    if (node >= N_NODES) return;
    int p = offs[node], e = offs[node + 1];
    unsigned int self = u[(size_t)node * 64 + lane];
    float ax0 = bf_lo(self), ay0 = bf_hi(self);
    float ax1 = 0.f, ay1 = 0.f, ax2 = 0.f, ay2 = 0.f, ax3 = 0.f, ay3 = 0.f;
    float ax4 = 0.f, ay4 = 0.f, ax5 = 0.f, ay5 = 0.f, ax6 = 0.f, ay6 = 0.f;
    float ax7 = 0.f, ay7 = 0.f;
    for (; p < e; p += 8) {
        int i1 = p + 1, i2 = p + 2, i3 = p + 3, i4 = p + 4, i5 = p + 5, i6 = p + 6, i7 = p + 7;
        int last = e - 1;
        int s0 = csr[p];
        int s1 = csr[i1 < e ? i1 : last];
        int s2 = csr[i2 < e ? i2 : last];
        int s3 = csr[i3 < e ? i3 : last];
        int s4 = csr[i4 < e ? i4 : last];
        int s5 = csr[i5 < e ? i5 : last];
        int s6 = csr[i6 < e ? i6 : last];
        int s7 = csr[i7 < e ? i7 : last];
        unsigned v0 = u[(size_t)s0 * 64 + lane];
        unsigned v1 = u[(size_t)s1 * 64 + lane];
        unsigned v2 = u[(size_t)s2 * 64 + lane];
        unsigned v3 = u[(size_t)s3 * 64 + lane];
        unsigned v4 = u[(size_t)s4 * 64 + lane];
        unsigned v5 = u[(size_t)s5 * 64 + lane];
        unsigned v6 = u[(size_t)s6 * 64 + lane];
        unsigned v7 = u[(size_t)s7 * 64 + lane];
        float m1 = (i1 < e) ? 1.f : 0.f;
        float m2 = (i2 < e) ? 1.f : 0.f;
        float m3 = (i3 < e) ? 1.f : 0.f;
        float m4 = (i4 < e) ? 1.f : 0.f;
        float m5 = (i5 < e) ? 1.f : 0.f;
        float m6 = (i6 < e) ? 1.f : 0.f;
        float m7 = (i7 < e) ? 1.f : 0.f;
        ax0 += bf_lo(v0);               ay0 += bf_hi(v0);
        ax1 = fmaf(m1, bf_lo(v1), ax1); ay1 = fmaf(m1, bf_hi(v1), ay1);
        ax2 = fmaf(m2, bf_lo(v2), ax2); ay2 = fmaf(m2, bf_hi(v2), ay2);
        ax3 = fmaf(m3, bf_lo(v3), ax3); ay3 = fmaf(m3, bf_hi(v3), ay3);
        ax4 = fmaf(m4, bf_lo(v4), ax4); ay4 = fmaf(m4, bf_hi(v4), ay4);
        ax5 = fmaf(m5, bf_lo(v5), ax5); ay5 = fmaf(m5, bf_hi(v5), ay5);
        ax6 = fmaf(m6, bf_lo(v6), ax6); ay6 = fmaf(m6, bf_hi(v6), ay6);
        ax7 = fmaf(m7, bf_lo(v7), ax7); ay7 = fmaf(m7, bf_hi(v7), ay7);
    }
    float d = dinv[node];
    float2 b = ((const float2*)bias)[lane];
    float sx = ((ax0 + ax1) + (ax2 + ax3)) + ((ax4 + ax5) + (ax6 + ax7));
    float sy = ((ay0 + ay1) + (ay2 + ay3)) + ((ay4 + ay5) + (ay6 + ay7));
    float r0 = fmaxf(d * sx + b.x, 0.f);
    float r1 = fmaxf(d * sy + b.y, 0.f);
    ((float2*)hout)[(size_t)node * 64 + lane] = make_float2(r0, r1);
}

// ---------------- pool (batch sorted) + linear head ----------------
__global__ __launch_bounds__(128) void k_pool(const float* __restrict__ h,
                                              const int* __restrict__ batch,
                                              const float* __restrict__ Wl,
                                              const float* __restrict__ bl,
                                              float* __restrict__ out) {
    int g = blockIdx.x;
    int c = threadIdx.x;
    __shared__ int sb[2];
    if (c < 2) {
        int tgt = g + c;
        int lo = 0, hi = N_NODES;
        while (lo < hi) { int m = (lo + hi) >> 1; if (batch[m] < tgt) lo = m + 1; else hi = m; }
        sb[c] = lo;
    }
    __syncthreads();
    int s0 = sb[0], s1 = sb[1];
    float sum = 0.f;
    for (int i = s0; i < s1; ++i) sum += h[(size_t)i * 128 + c];
    float cnt = (float)(s1 - s0);
    float pooled = sum / fmaxf(cnt, 1.0f);
    __shared__ float red[128];
    float w0 = Wl[c * 2 + 0], w1 = Wl[c * 2 + 1];
    red[c] = pooled * w0;
    __syncthreads();
    for (int st = 64; st > 0; st >>= 1) { if (c < st) red[c] += red[c + st]; __syncthreads(); }
    if (c == 0) out[g * 2 + 0] = red[0] + bl[0];
    __syncthreads();
    red[c] = pooled * w1;
    __syncthreads();
    for (int st = 64; st > 0; st >>= 1) { if (c < st) red[c] += red[c + st]; __syncthreads(); }
    if (c == 0) out[g * 2 + 1] = red[0] + bl[1];
}

extern "C" void kernel_launch(void* const* d_in, const int* in_sizes, int n_in,
                              void* d_out, int out_size, void* d_ws, size_t ws_size,
                              hipStream_t stream) {
    const float* x  = (const float*)d_in[0];
    const int* ei   = (const int*)d_in[1];
    const int* batch = (const int*)d_in[2];
    const float* W1 = (const float*)d_in[3];
    const float* b1 = (const float*)d_in[4];
    const float* W2 = (const float*)d_in[5];
    const float* b2 = (const float*)d_in[6];
    const float* Wl = (const float*)d_in[7];
    const float* bl = (const float*)d_in[8];
    float* out = (float*)d_out;
    const int* src = ei;
    const int* dst = ei + N_EDGES;

    char* ws = (char*)d_ws;
    size_t o = 0;
    auto alloc = [&](size_t bytes) -> void* {
        o = (o + 255) & ~(size_t)255;
        void* p = ws + o;
        o += bytes;
        return p;
    };
    int* bcount = (int*)alloc((size_t)NBUCK * 4);
    int* bbase  = (int*)alloc((size_t)NBUCK * 4);
    int* bcur   = (int*)alloc((size_t)NBUCK * 4);
    int* wsum   = (int*)alloc((size_t)NBUCK * 4);
    int* wbase  = (int*)alloc((size_t)NBUCK * 4);
    int* deg    = (int*)alloc((size_t)N_NODES * 4);
    float* dinv = (float*)alloc((size_t)N_NODES * 4);
    int* offs   = (int*)alloc((size_t)(N_NODES + 1) * 4);
    unsigned short* wp1 = (unsigned short*)alloc(65536);
    unsigned short* wp2 = (unsigned short*)alloc(65536);
    uint2* pairs = (uint2*)alloc((size_t)N_EDGES * 8);
    int* csr    = (int*)alloc((size_t)N_EDGES * 4);
    unsigned short* u = (unsigned short*)alloc((size_t)N_NODES * 128 * 2);  // bf16
    float* h    = (float*)alloc((size_t)N_NODES * 128 * 4);

    hipMemsetAsync(bcount, 0, (size_t)NBUCK * 4, stream);
    k_prepW<<<64, 256, 0, stream>>>(W1, wp1);
    k_prepW<<<64, 256, 0, stream>>>(W2, wp2);
    k_hist<<<256, 256, 0, stream>>>(dst, bcount);
    k_scan391<<<1, 512, 0, stream>>>(bcount, bbase, bcur, nullptr);
    k_bucket<<<(N_EDGES + CHUNK - 1) / CHUNK, 256, 0, stream>>>(src, dst, bcur, pairs);
    k_bdeg<<<NBUCK, 256, 0, stream>>>(pairs, bbase, bcount, deg, dinv, wsum);
    k_scan391<<<1, 512, 0, stream>>>(wsum, wbase, nullptr, &offs[N_NODES]);
    k_bfill<<<NBUCK, 256, 0, stream>>>(pairs, bbase, bcount, deg, wbase, offs, csr);

    const int gemmGrid = (N_NODES + 63) / 64;  // 1563
    k_gemm_mfma<<<gemmGrid, 256, 0, stream>>>(x, wp1, dinv, u);
    k_agg<<<(N_NODES + 3) / 4, 256, 0, stream>>>((const unsigned int*)u, offs, csr, dinv, b1, h);
    k_gemm_mfma<<<gemmGrid, 256, 0, stream>>>(h, wp2, dinv, u);
    k_agg<<<(N_NODES + 3) / 4, 256, 0, stream>>>((const unsigned int*)u, offs, csr, dinv, b2, h);

    k_pool<<<N_GRAPHS, 128, 0, stream>>>(h, batch, Wl, bl, out);
}

// Round 6
// 375.160 us; speedup vs baseline: 2.1698x; 1.0210x over previous
//
#include <hip/hip_runtime.h>
#include <hip/hip_bf16.h>

#define N_NODES 100000
#define N_EDGES 1600000
#define FEAT 128
#define N_GRAPHS 1024
#define NBUCK 391   // ceil(N_NODES/256) windows of 256 nodes (bucket = dst >> 8)
#define CHUNK 4096  // edges per k_bucket block

typedef short short8 __attribute__((ext_vector_type(8)));
typedef float float4v __attribute__((ext_vector_type(4)));

static __device__ inline unsigned short f2bf(float f) {
    __hip_bfloat16 b = __float2bfloat16(f);
    unsigned short r;
    __builtin_memcpy(&r, &b, 2);
    return r;
}
static __device__ inline float bf_lo(unsigned int v) { return __uint_as_float(v << 16); }
static __device__ inline float bf_hi(unsigned int v) { return __uint_as_float(v & 0xFFFF0000u); }

// ---------------- bucket histogram (LDS-staged) ----------------
__global__ __launch_bounds__(256) void k_hist(const int* __restrict__ dst,
                                              int* __restrict__ bcount) {
    __shared__ int h[NBUCK];
    for (int i = threadIdx.x; i < NBUCK; i += 256) h[i] = 0;
    __syncthreads();
    for (int e = blockIdx.x * 256 + threadIdx.x; e < N_EDGES; e += gridDim.x * 256)
        atomicAdd(&h[dst[e] >> 8], 1);
    __syncthreads();
    for (int i = threadIdx.x; i < NBUCK; i += 256) {
        int c = h[i];
        if (c) atomicAdd(&bcount[i], c);
    }
}

// ---------------- exclusive scan of 391 values (single block) ----------------
__global__ __launch_bounds__(512) void k_scan391(const int* __restrict__ in,
                                                 int* __restrict__ base,
                                                 int* __restrict__ cur,
                                                 int* __restrict__ tail) {
    int t = threadIdx.x;
    int v = (t < NBUCK) ? in[t] : 0;
    int lane = t & 63, wid = t >> 6;
    int s = v;
#pragma unroll
    for (int d = 1; d < 64; d <<= 1) { int n = __shfl_up(s, d); if (lane >= d) s += n; }
    __shared__ int ws[8];
    if (lane == 63) ws[wid] = s;
    __syncthreads();
    if (t < 8) {
        int x = ws[t];
#pragma unroll
        for (int d = 1; d < 8; d <<= 1) { int n = __shfl_up(x, d); if ((int)t >= d) x += n; }
        ws[t] = x;
    }
    __syncthreads();
    int excl = s - v + (wid ? ws[wid - 1] : 0);
    if (t < NBUCK) {
        base[t] = excl;
        if (cur) cur[t] = excl;
    }
    if (t == 0 && tail) tail[0] = N_EDGES;
}

// ---------------- bin edges into bucket runs (block counting-sort) ----------------
__global__ __launch_bounds__(256) void k_bucket(const int* __restrict__ src,
                                                const int* __restrict__ dst,
                                                int* __restrict__ bcur,
                                                uint2* __restrict__ pairs) {
    __shared__ int cnt[NBUCK];
    __shared__ int basebuf[NBUCK];
    int t = threadIdx.x;
    int e0 = blockIdx.x * CHUNK;
    for (int i = t; i < NBUCK; i += 256) cnt[i] = 0;
    __syncthreads();
    int es[16], ed[16];
#pragma unroll
    for (int j = 0; j < 16; ++j) {
        int e = e0 + j * 256 + t;
        if (e < N_EDGES) {
            es[j] = src[e];
            ed[j] = dst[e];
            atomicAdd(&cnt[ed[j] >> 8], 1);
        } else ed[j] = -1;
    }
    __syncthreads();
    for (int i = t; i < NBUCK; i += 256) {
        int c = cnt[i];
        basebuf[i] = c ? atomicAdd(&bcur[i], c) : 0;
        cnt[i] = 0;
    }
    __syncthreads();
#pragma unroll
    for (int j = 0; j < 16; ++j) {
        if (ed[j] >= 0) {
            int b = ed[j] >> 8;
            int p = basebuf[b] + atomicAdd(&cnt[b], 1);
            pairs[p] = make_uint2((unsigned)es[j], (unsigned)ed[j]);
        }
    }
}

// ---------------- per-bucket degree via LDS atomics (+ fused dinv) ----------------
__global__ __launch_bounds__(256) void k_bdeg(const uint2* __restrict__ pairs,
                                              const int* __restrict__ bbase,
                                              const int* __restrict__ bcount,
                                              int* __restrict__ deg,
                                              float* __restrict__ dinv,
                                              int* __restrict__ wsum) {
    __shared__ int d[256];
    __shared__ int wr[4];
    int b = blockIdx.x, t = threadIdx.x;
    d[t] = 0;
    __syncthreads();
    int s0 = bbase[b], n = bcount[b];
    for (int i = t; i < n; i += 256) atomicAdd(&d[pairs[s0 + i].y & 255], 1);
    __syncthreads();
    int node = b * 256 + t;
    int v = d[t];
    if (node < N_NODES) {
        deg[node] = v;
        dinv[node] = rsqrtf((float)(v + 1));  // +1 self-loop
    }
#pragma unroll
    for (int dd = 32; dd > 0; dd >>= 1) v += __shfl_down(v, dd);
    if ((t & 63) == 0) wr[t >> 6] = v;
    __syncthreads();
    if (t == 0) wsum[b] = wr[0] + wr[1] + wr[2] + wr[3];
}

// ---------------- per-bucket CSR fill (L2-local scatter) ----------------
__global__ __launch_bounds__(256) void k_bfill(const uint2* __restrict__ pairs,
                                               const int* __restrict__ bbase,
                                               const int* __restrict__ bcount,
                                               const int* __restrict__ deg,
                                               const int* __restrict__ wbase,
                                               int* __restrict__ offs,
                                               int* __restrict__ csr) {
    __shared__ int lcur[256];
    __shared__ int ws[4];
    int b = blockIdx.x, t = threadIdx.x;
    int node = b * 256 + t;
    int dv = (node < N_NODES) ? deg[node] : 0;
    int lane = t & 63, wid = t >> 6;
    int s = dv;
#pragma unroll
    for (int d = 1; d < 64; d <<= 1) { int n = __shfl_up(s, d); if (lane >= d) s += n; }
    if (lane == 63) ws[wid] = s;
    __syncthreads();
    if (t < 4) {
        int x = ws[t];
#pragma unroll
        for (int d = 1; d < 4; d <<= 1) { int n = __shfl_up(x, d); if ((int)t >= d) x += n; }
        ws[t] = x;
    }
    __syncthreads();
    int excl = s - dv + (wid ? ws[wid - 1] : 0) + wbase[b];
    if (node < N_NODES) offs[node] = excl;
    lcur[t] = excl;
    __syncthreads();
    int s0 = bbase[b], n = bcount[b];
    for (int i = t; i < n; i += 256) {
        uint2 pr = pairs[s0 + i];
        int p = atomicAdd(&lcur[pr.y & 255], 1);
        csr[p] = (int)pr.x;
    }
}

// ---------------- W prep: split fp32 W[128x128] into hi/lo bf16, transposed+swizzled ----------
__global__ __launch_bounds__(256) void k_prepW(const float* __restrict__ W,
                                               unsigned short* __restrict__ wp) {
    int t = blockIdx.x * 256 + threadIdx.x;
    if (t >= 16384) return;
    int k = t >> 7, n = t & 127;
    float w = W[k * 128 + n];
    unsigned ub = __float_as_uint(w);
    unsigned short hi = (unsigned short)(ub >> 16);  // truncation split
    float hif = __uint_as_float(ub & 0xFFFF0000u);
    unsigned short lo = f2bf(w - hif);               // RNE residual
    int sidx = n * 128 + ((k & 7) | (8 * (((k >> 3) ^ n) & 15)));
    wp[sidx] = hi;
    wp[16384 + sidx] = lo;
}

// ---------------- MFMA GEMM: u = bf16( dinv .* (inp @ W) ) ----------------
__global__ __launch_bounds__(256) void k_gemm_mfma(const float* __restrict__ inp,
                                                   const unsigned short* __restrict__ wp,
                                                   const float* __restrict__ dinv,
                                                   unsigned short* __restrict__ u) {
    __shared__ unsigned short sW[32768];  // 64 KB: [0..16383]=hi, [16384..]=lo (swizzled)
    {
        float4* d4 = (float4*)sW;
        const float4* s4 = (const float4*)wp;
#pragma unroll
        for (int i = 0; i < 16; ++i) d4[threadIdx.x + 256 * i] = s4[threadIdx.x + 256 * i];
    }
    __syncthreads();
    const int t = threadIdx.x;
    const int wv = t >> 6, L = t & 63;
    const int m = L & 15, q = L >> 4;
    const int r0 = blockIdx.x * 64 + wv * 16;
    int arow = r0 + m;
    if (arow >= N_NODES) arow = N_NODES - 1;
    const float4* ap = (const float4*)(inp + (size_t)arow * 128);
    float4v acc[8];
#pragma unroll
    for (int c = 0; c < 8; ++c) acc[c] = (float4v){0.f, 0.f, 0.f, 0.f};

#pragma unroll
    for (int k0 = 0; k0 < 128; k0 += 32) {
        float4 f0 = ap[(k0 >> 2) + 2 * q];
        float4 f1 = ap[(k0 >> 2) + 2 * q + 1];
        float fa[8] = {f0.x, f0.y, f0.z, f0.w, f1.x, f1.y, f1.z, f1.w};
        short8 ah, al;
#pragma unroll
        for (int j = 0; j < 8; ++j) {
            unsigned ub = __float_as_uint(fa[j]);
            ah[j] = (short)(ub >> 16);
            float hif = __uint_as_float(ub & 0xFFFF0000u);
            al[j] = (short)f2bf(fa[j] - hif);
        }
        const int b = (k0 >> 3) + q;
#pragma unroll
        for (int c = 0; c < 8; ++c) {
            int ng = c * 16 + m;
            int elem = ng * 128 + 8 * ((b ^ ng) & 15);
            short8 bh = *(const short8*)&sW[elem];
            short8 bl = *(const short8*)&sW[16384 + elem];
            acc[c] = __builtin_amdgcn_mfma_f32_16x16x32_bf16(ah, bh, acc[c], 0, 0, 0);
            acc[c] = __builtin_amdgcn_mfma_f32_16x16x32_bf16(al, bh, acc[c], 0, 0, 0);
            acc[c] = __builtin_amdgcn_mfma_f32_16x16x32_bf16(ah, bl, acc[c], 0, 0, 0);
        }
    }
#pragma unroll
    for (int r = 0; r < 4; ++r) {
        int row = r0 + 4 * q + r;
        if (row < N_NODES) {
            float dv = dinv[row];
            unsigned short* up = u + (size_t)row * 128 + m;
#pragma unroll
            for (int c = 0; c < 8; ++c) up[c * 16] = f2bf(dv * acc[c][r]);
        }
    }
}

// ---------------- aggregate: h[i] = relu(dinv[i]*(sum_in u[src] + u[i]) + b) ----------------
// One wave per node; lane = 2 cols. p/e and csr indices are wave-uniform: forced scalar
// (readfirstlane) so csr reads ride the scalar pipe and tail slots s_cselect to the zeroed
// dummy row u[N_NODES] — no per-lane masks, 4 VALU/edge/lane (lshl, and, 2 fmac).
__global__ __launch_bounds__(256) void k_agg(const unsigned int* __restrict__ u,
                                             const int* __restrict__ offs,
                                             const int* __restrict__ csr,
                                             const float* __restrict__ dinv,
                                             const float* __restrict__ bias,
                                             float* __restrict__ hout) {
    int wid = threadIdx.x >> 6;
    int lane = threadIdx.x & 63;
    int node = __builtin_amdgcn_readfirstlane(blockIdx.x * 4 + wid);
    if (node >= N_NODES) return;
    int p = __builtin_amdgcn_readfirstlane(offs[node]);
    int e = __builtin_amdgcn_readfirstlane(offs[node + 1]);
    unsigned int self = u[(size_t)node * 64 + lane];
    float ax0 = bf_lo(self), ay0 = bf_hi(self);
    float ax1 = 0.f, ay1 = 0.f, ax2 = 0.f, ay2 = 0.f, ax3 = 0.f, ay3 = 0.f;
    float ax4 = 0.f, ay4 = 0.f, ax5 = 0.f, ay5 = 0.f, ax6 = 0.f, ay6 = 0.f;
    float ax7 = 0.f, ay7 = 0.f;
    for (; p < e; p += 8) {
        // unconditional scalar loads (csr padded by 8), scalar select to zero-row for tail
        int c0 = csr[p + 0], c1 = csr[p + 1], c2 = csr[p + 2], c3 = csr[p + 3];
        int c4 = csr[p + 4], c5 = csr[p + 5], c6 = csr[p + 6], c7 = csr[p + 7];
        int i0 = c0;
        int i1 = (p + 1 < e) ? c1 : N_NODES;
        int i2 = (p + 2 < e) ? c2 : N_NODES;
        int i3 = (p + 3 < e) ? c3 : N_NODES;
        int i4 = (p + 4 < e) ? c4 : N_NODES;
        int i5 = (p + 5 < e) ? c5 : N_NODES;
        int i6 = (p + 6 < e) ? c6 : N_NODES;
        int i7 = (p + 7 < e) ? c7 : N_NODES;
        unsigned v0 = (u + (size_t)i0 * 64)[lane];
        unsigned v1 = (u + (size_t)i1 * 64)[lane];
        unsigned v2 = (u + (size_t)i2 * 64)[lane];
        unsigned v3 = (u + (size_t)i3 * 64)[lane];
        unsigned v4 = (u + (size_t)i4 * 64)[lane];
        unsigned v5 = (u + (size_t)i5 * 64)[lane];
        unsigned v6 = (u + (size_t)i6 * 64)[lane];
        unsigned v7 = (u + (size_t)i7 * 64)[lane];
        ax0 += bf_lo(v0); ay0 += bf_hi(v0);
        ax1 += bf_lo(v1); ay1 += bf_hi(v1);
        ax2 += bf_lo(v2); ay2 += bf_hi(v2);
        ax3 += bf_lo(v3); ay3 += bf_hi(v3);
        ax4 += bf_lo(v4); ay4 += bf_hi(v4);
        ax5 += bf_lo(v5); ay5 += bf_hi(v5);
        ax6 += bf_lo(v6); ay6 += bf_hi(v6);
        ax7 += bf_lo(v7); ay7 += bf_hi(v7);
    }
    float d = dinv[node];
    float2 b = ((const float2*)bias)[lane];
    float sx = ((ax0 + ax1) + (ax2 + ax3)) + ((ax4 + ax5) + (ax6 + ax7));
    float sy = ((ay0 + ay1) + (ay2 + ay3)) + ((ay4 + ay5) + (ay6 + ay7));
    float r0 = fmaxf(d * sx + b.x, 0.f);
    float r1 = fmaxf(d * sy + b.y, 0.f);
    ((float2*)hout)[(size_t)node * 64 + lane] = make_float2(r0, r1);
}

// ---------------- pool (batch sorted) + linear head ----------------
__global__ __launch_bounds__(128) void k_pool(const float* __restrict__ h,
                                              const int* __restrict__ batch,
                                              const float* __restrict__ Wl,
                                              const float* __restrict__ bl,
                                              float* __restrict__ out) {
    int g = blockIdx.x;
    int c = threadIdx.x;
    __shared__ int sb[2];
    if (c < 2) {
        int tgt = g + c;
        int lo = 0, hi = N_NODES;
        while (lo < hi) { int m = (lo + hi) >> 1; if (batch[m] < tgt) lo = m + 1; else hi = m; }
        sb[c] = lo;
    }
    __syncthreads();
    int s0 = sb[0], s1 = sb[1];
    float sum = 0.f;
    for (int i = s0; i < s1; ++i) sum += h[(size_t)i * 128 + c];
    float cnt = (float)(s1 - s0);
    float pooled = sum / fmaxf(cnt, 1.0f);
    __shared__ float red[128];
    float w0 = Wl[c * 2 + 0], w1 = Wl[c * 2 + 1];
    red[c] = pooled * w0;
    __syncthreads();
    for (int st = 64; st > 0; st >>= 1) { if (c < st) red[c] += red[c + st]; __syncthreads(); }
    if (c == 0) out[g * 2 + 0] = red[0] + bl[0];
    __syncthreads();
    red[c] = pooled * w1;
    __syncthreads();
    for (int st = 64; st > 0; st >>= 1) { if (c < st) red[c] += red[c + st]; __syncthreads(); }
    if (c == 0) out[g * 2 + 1] = red[0] + bl[1];
}

extern "C" void kernel_launch(void* const* d_in, const int* in_sizes, int n_in,
                              void* d_out, int out_size, void* d_ws, size_t ws_size,
                              hipStream_t stream) {
    const float* x  = (const float*)d_in[0];
    const int* ei   = (const int*)d_in[1];
    const int* batch = (const int*)d_in[2];
    const float* W1 = (const float*)d_in[3];
    const float* b1 = (const float*)d_in[4];
    const float* W2 = (const float*)d_in[5];
    const float* b2 = (const float*)d_in[6];
    const float* Wl = (const float*)d_in[7];
    const float* bl = (const float*)d_in[8];
    float* out = (float*)d_out;
    const int* src = ei;
    const int* dst = ei + N_EDGES;

    char* ws = (char*)d_ws;
    size_t o = 0;
    auto alloc = [&](size_t bytes) -> void* {
        o = (o + 255) & ~(size_t)255;
        void* p = ws + o;
        o += bytes;
        return p;
    };
    int* bcount = (int*)alloc((size_t)NBUCK * 4);
    int* bbase  = (int*)alloc((size_t)NBUCK * 4);
    int* bcur   = (int*)alloc((size_t)NBUCK * 4);
    int* wsum   = (int*)alloc((size_t)NBUCK * 4);
    int* wbase  = (int*)alloc((size_t)NBUCK * 4);
    int* deg    = (int*)alloc((size_t)N_NODES * 4);
    float* dinv = (float*)alloc((size_t)N_NODES * 4);
    int* offs   = (int*)alloc((size_t)(N_NODES + 1) * 4);
    unsigned short* wp1 = (unsigned short*)alloc(65536);
    unsigned short* wp2 = (unsigned short*)alloc(65536);
    uint2* pairs = (uint2*)alloc((size_t)N_EDGES * 8);
    int* csr    = (int*)alloc((size_t)(N_EDGES + 8) * 4);               // +8 pad for unroll reads
    unsigned short* u = (unsigned short*)alloc((size_t)(N_NODES + 1) * 128 * 2);  // +1 zero row
    float* h    = (float*)alloc((size_t)N_NODES * 128 * 4);

    hipMemsetAsync(bcount, 0, (size_t)NBUCK * 4, stream);
    hipMemsetAsync(u + (size_t)N_NODES * 128, 0, 256, stream);  // zero dummy row
    k_prepW<<<64, 256, 0, stream>>>(W1, wp1);
    k_prepW<<<64, 256, 0, stream>>>(W2, wp2);
    k_hist<<<256, 256, 0, stream>>>(dst, bcount);
    k_scan391<<<1, 512, 0, stream>>>(bcount, bbase, bcur, nullptr);
    k_bucket<<<(N_EDGES + CHUNK - 1) / CHUNK, 256, 0, stream>>>(src, dst, bcur, pairs);
    k_bdeg<<<NBUCK, 256, 0, stream>>>(pairs, bbase, bcount, deg, dinv, wsum);
    k_scan391<<<1, 512, 0, stream>>>(wsum, wbase, nullptr, &offs[N_NODES]);
    k_bfill<<<NBUCK, 256, 0, stream>>>(pairs, bbase, bcount, deg, wbase, offs, csr);

    const int gemmGrid = (N_NODES + 63) / 64;  // 1563
    k_gemm_mfma<<<gemmGrid, 256, 0, stream>>>(x, wp1, dinv, u);
    k_agg<<<(N_NODES + 3) / 4, 256, 0, stream>>>((const unsigned int*)u, offs, csr, dinv, b1, h);
    k_gemm_mfma<<<gemmGrid, 256, 0, stream>>>(h, wp2, dinv, u);
    k_agg<<<(N_NODES + 3) / 4, 256, 0, stream>>>((const unsigned int*)u, offs, csr, dinv, b2, h);

    k_pool<<<N_GRAPHS, 128, 0, stream>>>(h, batch, Wl, bl, out);
}

// Round 7
// 366.498 us; speedup vs baseline: 2.2211x; 1.0236x over previous
//
#include <hip/hip_runtime.h>
#include <hip/hip_bf16.h>

#define N_NODES 100000
#define N_EDGES 1600000
#define FEAT 128
#define N_GRAPHS 1024
#define NBUCK 391   // ceil(N_NODES/256) windows of 256 nodes (bucket = dst >> 8)
#define CHUNK 4096  // edges per k_bucket block

typedef short short8 __attribute__((ext_vector_type(8)));
typedef float float4v __attribute__((ext_vector_type(4)));

static __device__ inline unsigned short f2bf(float f) {
    __hip_bfloat16 b = __float2bfloat16(f);
    unsigned short r;
    __builtin_memcpy(&r, &b, 2);
    return r;
}
static __device__ inline float bf_lo(unsigned int v) { return __uint_as_float(v << 16); }
static __device__ inline float bf_hi(unsigned int v) { return __uint_as_float(v & 0xFFFF0000u); }
static __device__ inline float bf_s(unsigned short s) { return __uint_as_float(((unsigned)s) << 16); }

// ---------------- fused prep: split W1/W2 to hi/lo bf16 (transposed+swizzled), zero bcount + u dummy row ----
// Element (k,n) -> index n*128 + ((k&7) | 8*(((k>>3) ^ n) & 15)); wp[0..16383]=hi, [16384..]=lo.
__global__ __launch_bounds__(256) void k_prep(const float* __restrict__ W1,
                                              const float* __restrict__ W2,
                                              unsigned short* __restrict__ wp1,
                                              unsigned short* __restrict__ wp2,
                                              int* __restrict__ bcount,
                                              unsigned int* __restrict__ udummy) {
    int bid = blockIdx.x;
    const float* W = (bid < 64) ? W1 : W2;
    unsigned short* wp = (bid < 64) ? wp1 : wp2;
    int t = (bid & 63) * 256 + threadIdx.x;  // 0..16383
    int k = t >> 7, n = t & 127;
    float w = W[k * 128 + n];
    unsigned ub = __float_as_uint(w);
    unsigned short hi = (unsigned short)(ub >> 16);  // truncation split
    float hif = __uint_as_float(ub & 0xFFFF0000u);
    unsigned short lo = f2bf(w - hif);               // RNE residual
    int sidx = n * 128 + ((k & 7) | (8 * (((k >> 3) ^ n) & 15)));
    wp[sidx] = hi;
    wp[16384 + sidx] = lo;
    if (bid == 0) {
        for (int i = threadIdx.x; i < NBUCK; i += 256) bcount[i] = 0;
        if (threadIdx.x < 64) udummy[threadIdx.x] = 0;
    }
}

// ---------------- bucket histogram (LDS-staged) ----------------
__global__ __launch_bounds__(256) void k_hist(const int* __restrict__ dst,
                                              int* __restrict__ bcount) {
    __shared__ int h[NBUCK];
    for (int i = threadIdx.x; i < NBUCK; i += 256) h[i] = 0;
    __syncthreads();
    for (int e = blockIdx.x * 256 + threadIdx.x; e < N_EDGES; e += gridDim.x * 256)
        atomicAdd(&h[dst[e] >> 8], 1);
    __syncthreads();
    for (int i = threadIdx.x; i < NBUCK; i += 256) {
        int c = h[i];
        if (c) atomicAdd(&bcount[i], c);
    }
}

// ---------------- exclusive scan of 391 values (single block) ----------------
__global__ __launch_bounds__(512) void k_scan391(const int* __restrict__ in,
                                                 int* __restrict__ base,
                                                 int* __restrict__ cur,
                                                 int* __restrict__ tail) {
    int t = threadIdx.x;
    int v = (t < NBUCK) ? in[t] : 0;
    int lane = t & 63, wid = t >> 6;
    int s = v;
#pragma unroll
    for (int d = 1; d < 64; d <<= 1) { int n = __shfl_up(s, d); if (lane >= d) s += n; }
    __shared__ int ws[8];
    if (lane == 63) ws[wid] = s;
    __syncthreads();
    if (t < 8) {
        int x = ws[t];
#pragma unroll
        for (int d = 1; d < 8; d <<= 1) { int n = __shfl_up(x, d); if ((int)t >= d) x += n; }
        ws[t] = x;
    }
    __syncthreads();
    int excl = s - v + (wid ? ws[wid - 1] : 0);
    if (t < NBUCK) {
        base[t] = excl;
        if (cur) cur[t] = excl;
    }
    if (t == 0 && tail) tail[0] = N_EDGES;
}

// ---------------- bin edges into bucket runs (block counting-sort), packed (src<<8)|dst8 ----------------
__global__ __launch_bounds__(256) void k_bucket(const int* __restrict__ src,
                                                const int* __restrict__ dst,
                                                int* __restrict__ bcur,
                                                unsigned int* __restrict__ pairs) {
    __shared__ int cnt[NBUCK];
    __shared__ int basebuf[NBUCK];
    int t = threadIdx.x;
    int e0 = blockIdx.x * CHUNK;
    for (int i = t; i < NBUCK; i += 256) cnt[i] = 0;
    __syncthreads();
    unsigned pk[16]; int bk[16];
#pragma unroll
    for (int j = 0; j < 16; ++j) {
        int e = e0 + j * 256 + t;
        if (e < N_EDGES) {
            int s = src[e], d = dst[e];
            bk[j] = d >> 8;
            pk[j] = ((unsigned)s << 8) | (unsigned)(d & 255);
            atomicAdd(&cnt[bk[j]], 1);
        } else bk[j] = -1;
    }
    __syncthreads();
    for (int i = t; i < NBUCK; i += 256) {
        int c = cnt[i];
        basebuf[i] = c ? atomicAdd(&bcur[i], c) : 0;
        cnt[i] = 0;
    }
    __syncthreads();
#pragma unroll
    for (int j = 0; j < 16; ++j) {
        if (bk[j] >= 0) {
            int p = basebuf[bk[j]] + atomicAdd(&cnt[bk[j]], 1);
            pairs[p] = pk[j];
        }
    }
}

// ---------------- per-bucket degree via LDS atomics (+ fused dinv) ----------------
__global__ __launch_bounds__(256) void k_bdeg(const unsigned int* __restrict__ pairs,
                                              const int* __restrict__ bbase,
                                              const int* __restrict__ bcount,
                                              int* __restrict__ deg,
                                              float* __restrict__ dinv,
                                              int* __restrict__ wsum) {
    __shared__ int d[256];
    __shared__ int wr[4];
    int b = blockIdx.x, t = threadIdx.x;
    d[t] = 0;
    __syncthreads();
    int s0 = bbase[b], n = bcount[b];
    for (int i = t; i < n; i += 256) atomicAdd(&d[pairs[s0 + i] & 255u], 1);
    __syncthreads();
    int node = b * 256 + t;
    int v = d[t];
    if (node < N_NODES) {
        deg[node] = v;
        dinv[node] = rsqrtf((float)(v + 1));  // +1 self-loop
    }
#pragma unroll
    for (int dd = 32; dd > 0; dd >>= 1) v += __shfl_down(v, dd);
    if ((t & 63) == 0) wr[t >> 6] = v;
    __syncthreads();
    if (t == 0) wsum[b] = wr[0] + wr[1] + wr[2] + wr[3];
}

// ---------------- per-bucket CSR fill (L2-local scatter) ----------------
__global__ __launch_bounds__(256) void k_bfill(const unsigned int* __restrict__ pairs,
                                               const int* __restrict__ bbase,
                                               const int* __restrict__ bcount,
                                               const int* __restrict__ deg,
                                               const int* __restrict__ wbase,
                                               int* __restrict__ offs,
                                               int* __restrict__ csr) {
    __shared__ int lcur[256];
    __shared__ int ws[4];
    int b = blockIdx.x, t = threadIdx.x;
    int node = b * 256 + t;
    int dv = (node < N_NODES) ? deg[node] : 0;
    int lane = t & 63, wid = t >> 6;
    int s = dv;
#pragma unroll
    for (int d = 1; d < 64; d <<= 1) { int n = __shfl_up(s, d); if (lane >= d) s += n; }
    if (lane == 63) ws[wid] = s;
    __syncthreads();
    if (t < 4) {
        int x = ws[t];
#pragma unroll
        for (int d = 1; d < 4; d <<= 1) { int n = __shfl_up(x, d); if ((int)t >= d) x += n; }
        ws[t] = x;
    }
    __syncthreads();
    int excl = s - dv + (wid ? ws[wid - 1] : 0) + wbase[b];
    if (node < N_NODES) offs[node] = excl;
    lcur[t] = excl;
    __syncthreads();
    int s0 = bbase[b], n = bcount[b];
    for (int i = t; i < n; i += 256) {
        unsigned pr = pairs[s0 + i];
        int p = atomicAdd(&lcur[pr & 255u], 1);
        csr[p] = (int)(pr >> 8);
    }
}

// ---------------- MFMA GEMM (fp32 input): u = bf16( dinv .* (inp @ W) ) ----------------
__global__ __launch_bounds__(256) void k_gemm_mfma(const float* __restrict__ inp,
                                                   const unsigned short* __restrict__ wp,
                                                   const float* __restrict__ dinv,
                                                   unsigned short* __restrict__ u) {
    __shared__ unsigned short sW[32768];  // 64 KB: [0..16383]=hi, [16384..]=lo (swizzled)
    {
        float4* d4 = (float4*)sW;
        const float4* s4 = (const float4*)wp;
#pragma unroll
        for (int i = 0; i < 16; ++i) d4[threadIdx.x + 256 * i] = s4[threadIdx.x + 256 * i];
    }
    __syncthreads();
    const int t = threadIdx.x;
    const int wv = t >> 6, L = t & 63;
    const int m = L & 15, q = L >> 4;
    const int r0 = blockIdx.x * 64 + wv * 16;
    int arow = r0 + m;
    if (arow >= N_NODES) arow = N_NODES - 1;
    const float4* ap = (const float4*)(inp + (size_t)arow * 128);
    float4v acc[8];
#pragma unroll
    for (int c = 0; c < 8; ++c) acc[c] = (float4v){0.f, 0.f, 0.f, 0.f};

#pragma unroll
    for (int k0 = 0; k0 < 128; k0 += 32) {
        float4 f0 = ap[(k0 >> 2) + 2 * q];
        float4 f1 = ap[(k0 >> 2) + 2 * q + 1];
        float fa[8] = {f0.x, f0.y, f0.z, f0.w, f1.x, f1.y, f1.z, f1.w};
        short8 ah, al;
#pragma unroll
        for (int j = 0; j < 8; ++j) {
            unsigned ub = __float_as_uint(fa[j]);
            ah[j] = (short)(ub >> 16);
            float hif = __uint_as_float(ub & 0xFFFF0000u);
            al[j] = (short)f2bf(fa[j] - hif);
        }
        const int b = (k0 >> 3) + q;
#pragma unroll
        for (int c = 0; c < 8; ++c) {
            int ng = c * 16 + m;
            int elem = ng * 128 + 8 * ((b ^ ng) & 15);
            short8 bh = *(const short8*)&sW[elem];
            short8 bl = *(const short8*)&sW[16384 + elem];
            acc[c] = __builtin_amdgcn_mfma_f32_16x16x32_bf16(ah, bh, acc[c], 0, 0, 0);
            acc[c] = __builtin_amdgcn_mfma_f32_16x16x32_bf16(al, bh, acc[c], 0, 0, 0);
            acc[c] = __builtin_amdgcn_mfma_f32_16x16x32_bf16(ah, bl, acc[c], 0, 0, 0);
        }
    }
#pragma unroll
    for (int r = 0; r < 4; ++r) {
        int row = r0 + 4 * q + r;
        if (row < N_NODES) {
            float dv = dinv[row];
            unsigned short* up = u + (size_t)row * 128 + m;
#pragma unroll
            for (int c = 0; c < 8; ++c) up[c * 16] = f2bf(dv * acc[c][r]);
        }
    }
}

// ---------------- MFMA GEMM (bf16 hi/lo plane input — no in-register split) ----------------
__global__ __launch_bounds__(256) void k_gemm_mfma_bf(const unsigned short* __restrict__ hh,
                                                      const unsigned short* __restrict__ hl,
                                                      const unsigned short* __restrict__ wp,
                                                      const float* __restrict__ dinv,
                                                      unsigned short* __restrict__ u) {
    __shared__ unsigned short sW[32768];
    {
        float4* d4 = (float4*)sW;
        const float4* s4 = (const float4*)wp;
#pragma unroll
        for (int i = 0; i < 16; ++i) d4[threadIdx.x + 256 * i] = s4[threadIdx.x + 256 * i];
    }
    __syncthreads();
    const int t = threadIdx.x;
    const int wv = t >> 6, L = t & 63;
    const int m = L & 15, q = L >> 4;
    const int r0 = blockIdx.x * 64 + wv * 16;
    int arow = r0 + m;
    if (arow >= N_NODES) arow = N_NODES - 1;
    const unsigned short* hhp = hh + (size_t)arow * 128 + 8 * q;
    const unsigned short* hlp = hl + (size_t)arow * 128 + 8 * q;
    float4v acc[8];
#pragma unroll
    for (int c = 0; c < 8; ++c) acc[c] = (float4v){0.f, 0.f, 0.f, 0.f};

#pragma unroll
    for (int k0 = 0; k0 < 128; k0 += 32) {
        short8 ah = *(const short8*)(hhp + k0);
        short8 al = *(const short8*)(hlp + k0);
        const int b = (k0 >> 3) + q;
#pragma unroll
        for (int c = 0; c < 8; ++c) {
            int ng = c * 16 + m;
            int elem = ng * 128 + 8 * ((b ^ ng) & 15);
            short8 bh = *(const short8*)&sW[elem];
            short8 bl = *(const short8*)&sW[16384 + elem];
            acc[c] = __builtin_amdgcn_mfma_f32_16x16x32_bf16(ah, bh, acc[c], 0, 0, 0);
            acc[c] = __builtin_amdgcn_mfma_f32_16x16x32_bf16(al, bh, acc[c], 0, 0, 0);
            acc[c] = __builtin_amdgcn_mfma_f32_16x16x32_bf16(ah, bl, acc[c], 0, 0, 0);
        }
    }
#pragma unroll
    for (int r = 0; r < 4; ++r) {
        int row = r0 + 4 * q + r;
        if (row < N_NODES) {
            float dv = dinv[row];
            unsigned short* up = u + (size_t)row * 128 + m;
#pragma unroll
            for (int c = 0; c < 8; ++c) up[c * 16] = f2bf(dv * acc[c][r]);
        }
    }
}

// ---------------- aggregate: h = relu(dinv*(sum u[src] + u[self]) + b), h emitted as hi/lo bf16 planes ----
__global__ __launch_bounds__(256) void k_agg(const unsigned int* __restrict__ u,
                                             const int* __restrict__ offs,
                                             const int* __restrict__ csr,
                                             const float* __restrict__ dinv,
                                             const float* __restrict__ bias,
                                             unsigned int* __restrict__ hhp,
                                             unsigned int* __restrict__ hlp) {
    int wid = threadIdx.x >> 6;
    int lane = threadIdx.x & 63;
    int node = __builtin_amdgcn_readfirstlane(blockIdx.x * 4 + wid);
    if (node >= N_NODES) return;
    int p = __builtin_amdgcn_readfirstlane(offs[node]);
    int e = __builtin_amdgcn_readfirstlane(offs[node + 1]);
    unsigned int self = u[(size_t)node * 64 + lane];
    float ax0 = bf_lo(self), ay0 = bf_hi(self);
    float ax1 = 0.f, ay1 = 0.f, ax2 = 0.f, ay2 = 0.f, ax3 = 0.f, ay3 = 0.f;
    float ax4 = 0.f, ay4 = 0.f, ax5 = 0.f, ay5 = 0.f, ax6 = 0.f, ay6 = 0.f;
    float ax7 = 0.f, ay7 = 0.f;
    for (; p < e; p += 8) {
        int c0 = csr[p + 0], c1 = csr[p + 1], c2 = csr[p + 2], c3 = csr[p + 3];
        int c4 = csr[p + 4], c5 = csr[p + 5], c6 = csr[p + 6], c7 = csr[p + 7];
        int i0 = c0;
        int i1 = (p + 1 < e) ? c1 : N_NODES;
        int i2 = (p + 2 < e) ? c2 : N_NODES;
        int i3 = (p + 3 < e) ? c3 : N_NODES;
        int i4 = (p + 4 < e) ? c4 : N_NODES;
        int i5 = (p + 5 < e) ? c5 : N_NODES;
        int i6 = (p + 6 < e) ? c6 : N_NODES;
        int i7 = (p + 7 < e) ? c7 : N_NODES;
        unsigned v0 = (u + (size_t)i0 * 64)[lane];
        unsigned v1 = (u + (size_t)i1 * 64)[lane];
        unsigned v2 = (u + (size_t)i2 * 64)[lane];
        unsigned v3 = (u + (size_t)i3 * 64)[lane];
        unsigned v4 = (u + (size_t)i4 * 64)[lane];
        unsigned v5 = (u + (size_t)i5 * 64)[lane];
        unsigned v6 = (u + (size_t)i6 * 64)[lane];
        unsigned v7 = (u + (size_t)i7 * 64)[lane];
        ax0 += bf_lo(v0); ay0 += bf_hi(v0);
        ax1 += bf_lo(v1); ay1 += bf_hi(v1);
        ax2 += bf_lo(v2); ay2 += bf_hi(v2);
        ax3 += bf_lo(v3); ay3 += bf_hi(v3);
        ax4 += bf_lo(v4); ay4 += bf_hi(v4);
        ax5 += bf_lo(v5); ay5 += bf_hi(v5);
        ax6 += bf_lo(v6); ay6 += bf_hi(v6);
        ax7 += bf_lo(v7); ay7 += bf_hi(v7);
    }
    float d = dinv[node];
    float2 b = ((const float2*)bias)[lane];
    float sx = ((ax0 + ax1) + (ax2 + ax3)) + ((ax4 + ax5) + (ax6 + ax7));
    float sy = ((ay0 + ay1) + (ay2 + ay3)) + ((ay4 + ay5) + (ay6 + ay7));
    float r0 = fmaxf(d * sx + b.x, 0.f);
    float r1 = fmaxf(d * sy + b.y, 0.f);
    // split to hi (truncate) / lo (RNE residual) planes — exact same hh+hl the gemm used before
    unsigned u0 = __float_as_uint(r0), u1 = __float_as_uint(r1);
    unsigned short h0 = (unsigned short)(u0 >> 16), h1 = (unsigned short)(u1 >> 16);
    float rf0 = __uint_as_float(u0 & 0xFFFF0000u), rf1 = __uint_as_float(u1 & 0xFFFF0000u);
    unsigned short l0 = f2bf(r0 - rf0), l1 = f2bf(r1 - rf1);
    hhp[(size_t)node * 64 + lane] = (unsigned)h0 | ((unsigned)h1 << 16);
    hlp[(size_t)node * 64 + lane] = (unsigned)l0 | ((unsigned)l1 << 16);
}

// ---------------- pool (batch sorted) + linear head; h = hh + hl planes ----------------
__global__ __launch_bounds__(128) void k_pool(const unsigned short* __restrict__ hh,
                                              const unsigned short* __restrict__ hl,
                                              const int* __restrict__ batch,
                                              const float* __restrict__ Wl,
                                              const float* __restrict__ bl,
                                              float* __restrict__ out) {
    int g = blockIdx.x;
    int c = threadIdx.x;
    __shared__ int sb[2];
    if (c < 2) {
        int tgt = g + c;
        int lo = 0, hi = N_NODES;
        while (lo < hi) { int m = (lo + hi) >> 1; if (batch[m] < tgt) lo = m + 1; else hi = m; }
        sb[c] = lo;
    }
    __syncthreads();
    int s0 = sb[0], s1 = sb[1];
    float sum = 0.f;
    for (int i = s0; i < s1; ++i) {
        float v = bf_s(hh[(size_t)i * 128 + c]) + bf_s(hl[(size_t)i * 128 + c]);
        sum += v;
    }
    float cnt = (float)(s1 - s0);
    float pooled = sum / fmaxf(cnt, 1.0f);
    __shared__ float red[128];
    float w0 = Wl[c * 2 + 0], w1 = Wl[c * 2 + 1];
    red[c] = pooled * w0;
    __syncthreads();
    for (int st = 64; st > 0; st >>= 1) { if (c < st) red[c] += red[c + st]; __syncthreads(); }
    if (c == 0) out[g * 2 + 0] = red[0] + bl[0];
    __syncthreads();
    red[c] = pooled * w1;
    __syncthreads();
    for (int st = 64; st > 0; st >>= 1) { if (c < st) red[c] += red[c + st]; __syncthreads(); }
    if (c == 0) out[g * 2 + 1] = red[0] + bl[1];
}

extern "C" void kernel_launch(void* const* d_in, const int* in_sizes, int n_in,
                              void* d_out, int out_size, void* d_ws, size_t ws_size,
                              hipStream_t stream) {
    const float* x  = (const float*)d_in[0];
    const int* ei   = (const int*)d_in[1];
    const int* batch = (const int*)d_in[2];
    const float* W1 = (const float*)d_in[3];
    const float* b1 = (const float*)d_in[4];
    const float* W2 = (const float*)d_in[5];
    const float* b2 = (const float*)d_in[6];
    const float* Wl = (const float*)d_in[7];
    const float* bl = (const float*)d_in[8];
    float* out = (float*)d_out;
    const int* src = ei;
    const int* dst = ei + N_EDGES;

    char* ws = (char*)d_ws;
    size_t o = 0;
    auto alloc = [&](size_t bytes) -> void* {
        o = (o + 255) & ~(size_t)255;
        void* p = ws + o;
        o += bytes;
        return p;
    };
    int* bcount = (int*)alloc((size_t)NBUCK * 4);
    int* bbase  = (int*)alloc((size_t)NBUCK * 4);
    int* bcur   = (int*)alloc((size_t)NBUCK * 4);
    int* wsum   = (int*)alloc((size_t)NBUCK * 4);
    int* wbase  = (int*)alloc((size_t)NBUCK * 4);
    int* deg    = (int*)alloc((size_t)N_NODES * 4);
    float* dinv = (float*)alloc((size_t)N_NODES * 4);
    int* offs   = (int*)alloc((size_t)(N_NODES + 1) * 4);
    unsigned short* wp1 = (unsigned short*)alloc(65536);
    unsigned short* wp2 = (unsigned short*)alloc(65536);
    unsigned int* pairs = (unsigned int*)alloc((size_t)N_EDGES * 4);
    int* csr    = (int*)alloc((size_t)(N_EDGES + 8) * 4);               // +8 pad for unroll reads
    unsigned short* u = (unsigned short*)alloc((size_t)(N_NODES + 1) * 128 * 2);  // +1 zero row
    unsigned short* hh = (unsigned short*)alloc((size_t)N_NODES * 128 * 2);
    unsigned short* hl = (unsigned short*)alloc((size_t)N_NODES * 128 * 2);

    k_prep<<<128, 256, 0, stream>>>(W1, W2, wp1, wp2, bcount,
                                    (unsigned int*)(u + (size_t)N_NODES * 128));
    k_hist<<<256, 256, 0, stream>>>(dst, bcount);
    k_scan391<<<1, 512, 0, stream>>>(bcount, bbase, bcur, nullptr);
    k_bucket<<<(N_EDGES + CHUNK - 1) / CHUNK, 256, 0, stream>>>(src, dst, bcur, pairs);
    k_bdeg<<<NBUCK, 256, 0, stream>>>(pairs, bbase, bcount, deg, dinv, wsum);
    k_scan391<<<1, 512, 0, stream>>>(wsum, wbase, nullptr, &offs[N_NODES]);
    k_bfill<<<NBUCK, 256, 0, stream>>>(pairs, bbase, bcount, deg, wbase, offs, csr);

    const int gemmGrid = (N_NODES + 63) / 64;  // 1563
    k_gemm_mfma<<<gemmGrid, 256, 0, stream>>>(x, wp1, dinv, u);
    k_agg<<<(N_NODES + 3) / 4, 256, 0, stream>>>((const unsigned int*)u, offs, csr, dinv, b1,
                                                 (unsigned int*)hh, (unsigned int*)hl);
    k_gemm_mfma_bf<<<gemmGrid, 256, 0, stream>>>(hh, hl, wp2, dinv, u);
    k_agg<<<(N_NODES + 3) / 4, 256, 0, stream>>>((const unsigned int*)u, offs, csr, dinv, b2,
                                                 (unsigned int*)hh, (unsigned int*)hl);

    k_pool<<<N_GRAPHS, 128, 0, stream>>>(hh, hl, batch, Wl, bl, out);
}